// Round 5
// baseline (362.755 us; speedup 1.0000x reference)
//
#include <hip/hip_runtime.h>
#include <hip/hip_bf16.h>
#include <math.h>
#include <stdint.h>

#define S    256
#define GN   128

typedef __attribute__((ext_vector_type(8))) short  short8;   // 8 bf16
typedef __attribute__((ext_vector_type(4))) float  floatx4;  // MFMA C/D
typedef __attribute__((ext_vector_type(2))) float  float2v;  // v_pk_*_f32 pair

// workspace layout (bytes)
#define WS_BHI 0          // ushort[4*4*64*8] = 16384 B  (f_w2 bf16, frag order)
#define WS_RW1 16384      // ushort[2*4*64*8] =  8192 B  (r_w1 bf16, frag order)
#define WS_B2S 24576      // float  (b2.s_w + s_b)
#define WS_WS2 24592      // float[128]  (W2 @ s_w, fp32)
#define WS_W1P 25104      // float[64*8] pair-interleaved layer-1 = 2048 B
#define WS_W2E 27152      // ushort[2*64*8] = 2048 B (r_w2^T bf16, A-frag order)

__device__ __forceinline__ unsigned short bf16_rtne(float f) {
    uint32_t u = __builtin_bit_cast(uint32_t, f);
    uint32_t r = (u + 0x7fffu + ((u >> 16) & 1u)) >> 16;
    return (unsigned short)r;
}
__device__ __forceinline__ uint32_t cvt_pk_bf16(float a, float b) {
    float2 hh; hh.x = a; hh.y = b;
    __hip_bfloat162 pk = __float22bfloat162_rn(hh);   // v_cvt_pk_bf16_f32
    uint32_t u; __builtin_memcpy(&u, &pk, 4);
    return u;
}

// ---------- pre-pack kernel: weights -> bf16 in MFMA fragment order ----------
__global__ __launch_bounds__(256)
void nerf_prep(const float* __restrict__ f_w1, const float* __restrict__ f_b1,
               const float* __restrict__ f_w2, const float* __restrict__ f_b2,
               const float* __restrict__ s_w,  const float* __restrict__ s_b,
               const float* __restrict__ r_w1, const float* __restrict__ r_w2,
               unsigned char* __restrict__ ws)
{
    const int tid = threadIdx.x;
    if (tid < 128) {                       // ws2 = W2 @ s_w  (fp32) -> global
        float acc = 0.0f;
        for (int n = 0; n < 64; ++n) acc += f_w2[tid * 64 + n] * s_w[n];
        ((float*)(ws + WS_WS2))[tid] = acc;
    } else if (tid == 128) {               // b2s = b2 . s_w + s_b
        float acc = s_b[0];
        for (int n = 0; n < 64; ++n) acc += f_b2[n] * s_w[n];
        *(float*)(ws + WS_B2S) = acc;
    }
    // layer-1 pair-interleaved pack: pair pp covers k=2pp,2pp+1:
    //   {wx0,wx1, wy0,wy1, wz0,wz1, b0,b1}  (aligned float2 pairs for v_pk_fma)
    {
        float* w1pk = (float*)(ws + WS_W1P);
        for (int pp = tid; pp < 64; pp += 256) {
            int k0 = 2 * pp, k1 = 2 * pp + 1;
            w1pk[pp * 8 + 0] = f_w1[k0];       w1pk[pp * 8 + 1] = f_w1[k1];
            w1pk[pp * 8 + 2] = f_w1[128 + k0]; w1pk[pp * 8 + 3] = f_w1[128 + k1];
            w1pk[pp * 8 + 4] = f_w1[256 + k0]; w1pk[pp * 8 + 5] = f_w1[256 + k1];
            w1pk[pp * 8 + 6] = f_b1[k0];       w1pk[pp * 8 + 7] = f_b1[k1];
        }
    }

    unsigned short* bhi = (unsigned short*)(ws + WS_BHI);
    for (int i = tid; i < 8192; i += 256) {
        int j = i & 7, L = (i >> 3) & 63, g = i >> 9;   // g = kc*4 + tn
        int tn = g & 3, kc = g >> 2;
        int q = L >> 4, cc = L & 15;
        int k = kc * 32 + q * 8 + j;
        bhi[i] = bf16_rtne(f_w2[k * 64 + tn * 16 + cc]);
    }
    unsigned short* rw = (unsigned short*)(ws + WS_RW1);
    for (int i = tid; i < 4096; i += 256) {
        int j = i & 7, L = (i >> 3) & 63, g = i >> 9;   // g = ks*4 + tn
        int tn = g & 3, ks = g >> 2;
        int q = L >> 4, cc = L & 15;
        int k = ks * 32 + q * 8 + j;
        rw[i] = bf16_rtne(r_w1[k * 64 + tn * 16 + cc]);
    }
    // r_w2^T in A-fragment order for the phase-E MFMA:
    // A[row=out-channel][k=hidden]; rows 3..15 zero.
    unsigned short* w2e = (unsigned short*)(ws + WS_W2E);
    for (int i = tid; i < 1024; i += 256) {
        int j = i & 7, L = (i >> 3) & 63, kf = i >> 9;
        int q = L >> 4, ch = L & 15;
        int k = kf * 32 + q * 8 + j;
        w2e[i] = (ch < 3) ? bf16_rtne(r_w2[k * 3 + ch]) : (unsigned short)0;
    }
}

// ---------------------------- main kernel -----------------------------------
// R22 = R21 + latency restructure (occupancy chase abandoned after R21 showed
// dur/occupancy insensitive to the 4->5 block LDS cap raise).
// Theory: ~45% of cycles are serial global-load dependency stalls that all
// lockstep waves hit together:
//  (1) phase B bhi B-frags were global loads consumed immediately by MFMA
//      -> hand-unrolled kc pipeline, two named reg sets, next-kc loads issue
//      BEFORE the ~220-cycle h-compute of the current kc,
//  (2) phase D rb frags bulk-loaded at pass top (before LDS afr + MFMAs),
//  (3) the out[]-slot scan round-trip (write->barrier->read) now straddles
//      phase D: slot-write before, barrier+read after -- phase D has no
//      dependence on the scan result (weight only feeds phase E),
//  (4) b2v/b2s hoisted to phase A.
// Tripwire: WRITE_SIZE must stay ~1.3 MB (pipeline regs must not spill).
__global__ __launch_bounds__(256, 4)
void nerf_mfma(const float* __restrict__ rays_o,
               const float* __restrict__ rays_d,
               const float* __restrict__ grid,
               const float* __restrict__ f_b2,
               const float* __restrict__ r_w1,
               const float* __restrict__ r_b1,
               const float* __restrict__ r_b2,
               const unsigned char* __restrict__ ws,
               float* __restrict__ out)
{
    // fh: bf16 [256 rows][64], XOR-swizzled in 8-ushort groups: conflict-free
    // b128. 32768 B exactly = the ONLY LDS object -> LDS never the limiter.
    __shared__ __align__(16) unsigned short fh[256 * 64];
    unsigned char* fhB = (unsigned char*)fh;

    const int tid   = threadIdx.x;
    const int ray   = blockIdx.x;
    const int lane  = tid & 63;
    const int wv    = tid >> 6;
    const int q     = lane >> 4;
    const int c     = lane & 15;
    const int mbase = wv * 64;
    const int d01   = 72 - ((c >> 3) << 4);   // i1 - i0 in the epilogue swizzle

    // stage layer-1 pack (2 KB) + ws2 (512 B) into fh rows 32..63 region
    if (tid < 128) {
        ((float4*)(fhB + 4096))[tid] = ((const float4*)(ws + WS_W1P))[tid];
        ((float*)(fhB + 6144))[tid]  = ((const float*)(ws + WS_WS2))[tid];
    }

    // uniform loads issued early; latency hides under phase A
    float b2s  = *(const float*)(ws + WS_B2S);
    float b2v0 = f_b2[c], b2v1 = f_b2[16 + c], b2v2 = f_b2[32 + c], b2v3 = f_b2[48 + c];

    // ---------------- Phase A: geometry + grid sample (thread = sample) ------
    const float stop = 1.0f - 1.0f / (float)(S + 2);
    const float step = stop / (float)S;
    float u0 = (float)tid * step;
    float u1 = (float)(tid + 1) * step;
    float t    = (u0 < 0.5f) ? 2.0f * u0 : 1.0f / (2.0f - 2.0f * u0);
    float tn_  = (u1 < 0.5f) ? 2.0f * u1 : 1.0f / (2.0f - 2.0f * u1);
    float dist = tn_ - t;

    float ox = rays_o[ray * 3 + 0], oy = rays_o[ray * 3 + 1], oz = rays_o[ray * 3 + 2];
    float dxv = rays_d[ray * 3 + 0], dyv = rays_d[ray * 3 + 1], dzv = rays_d[ray * 3 + 2];

    float px = ox + dxv * t, py = oy + dyv * t, pz = oz + dzv * t;
    float nrm = sqrtf(px * px + py * py + pz * pz);
    float scale = (nrm <= 1.0f) ? 0.5f : (2.0f - 1.0f / nrm) / nrm * 0.5f;
    float cx = px * scale, cy = py * scale, cz = pz * scale;

    float ix = ((cx + 1.0f) * (float)GN - 1.0f) * 0.5f;
    float iy = ((cy + 1.0f) * (float)GN - 1.0f) * 0.5f;
    float iz = ((cz + 1.0f) * (float)GN - 1.0f) * 0.5f;
    float fx0 = floorf(ix), fy0 = floorf(iy), fz0 = floorf(iz);
    float fx = ix - fx0, fy = iy - fy0, fz = iz - fz0;
    int x0 = (int)fx0, y0 = (int)fy0, z0 = (int)fz0;
    int x1 = x0 + 1, y1 = y0 + 1, z1 = z0 + 1;

    // branchless clamped trilinear (bit-exact vs branchy version)
    float wxv[2], wyv[2], wzv[2];
    wxv[0] = (x0 >= 0) ? (1.0f - fx) : 0.0f;  wxv[1] = (x1 < GN) ? fx : 0.0f;
    wyv[0] = (y0 >= 0) ? (1.0f - fy) : 0.0f;  wyv[1] = (y1 < GN) ? fy : 0.0f;
    wzv[0] = (z0 >= 0) ? (1.0f - fz) : 0.0f;  wzv[1] = (z1 < GN) ? fz : 0.0f;
    int xc[2], yb[2], zb[2];
    xc[0] = (x0 < 0) ? 0 : x0;              xc[1] = (x1 > GN - 1) ? GN - 1 : x1;
    yb[0] = ((y0 < 0) ? 0 : y0) * GN;       yb[1] = ((y1 > GN - 1) ? GN - 1 : y1) * GN;
    zb[0] = ((z0 < 0) ? 0 : z0) * (GN*GN);  zb[1] = ((z1 > GN - 1) ? GN - 1 : z1) * (GN*GN);

    float occ = 0.0f;
    #pragma unroll
    for (int dzc = 0; dzc < 2; ++dzc)
    #pragma unroll
    for (int dyc = 0; dyc < 2; ++dyc)
    #pragma unroll
    for (int dxc = 0; dxc < 2; ++dxc) {
        float w = (wxv[dxc] * wyv[dyc]) * wzv[dzc];
        occ += w * grid[zb[dzc] + yb[dyc] + xc[dxc]];
    }
    bool maskA = occ > 0.01f;

    __syncthreads();   // w1p / ws2 staged into fh region

    // ------- Phase B+C: feat GEMM in two tm-passes (acc[2][4] = 32 AGPR) -----
    const unsigned short* __restrict__ bhiP = (const unsigned short*)(ws + WS_BHI);
    float sgv[4] = {0.0f, 0.0f, 0.0f, 0.0f};   // all reads/writes literal-indexed

// load the 4 B-frags of K-chunk KC into named regs (global, L2-hot)
#define LOADB(D0, D1, D2, D3, KC) { \
        const short8* bp_ = (const short8*)(bhiP + (KC) * 2048 + lane * 8); \
        D0 = bp_[0]; D1 = bp_[64]; D2 = bp_[128]; D3 = bp_[192]; }

// one kc step: (optionally) issue next-kc loads, compute h-block, MFMA with
// the B-frags loaded one step earlier. All indices literal after unroll.
#define KC_STEP(KC, B0, B1, B2, B3, ...) { \
        const int k0_  = (KC) * 32 + q * 8; \
        const int pp0_ = (KC) * 16 + q * 4; \
        const float4* w1q4_ = (const float4*)(fhB + 4096 + pp0_ * 32); \
        float ws2r_[8]; \
        *(float4*)(ws2r_)     = *(const float4*)(fhB + 6144 + k0_ * 4); \
        *(float4*)(ws2r_ + 4) = *(const float4*)(fhB + 6144 + k0_ * 4 + 16); \
        __VA_ARGS__ \
        uint32_t packed_[2][4]; \
        _Pragma("unroll") \
        for (int p = 0; p < 4; ++p) { \
            float4 q0_ = w1q4_[2 * p]; \
            float4 q1_ = w1q4_[2 * p + 1]; \
            float2v wx2_ = {q0_.x, q0_.y}; \
            float2v wy2_ = {q0_.z, q0_.w}; \
            float2v wz2_ = {q1_.x, q1_.y}; \
            float2v bb2_ = {q1_.z, q1_.w}; \
            float2v wsp_ = {ws2r_[2 * p], ws2r_[2 * p + 1]}; \
            _Pragma("unroll") \
            for (int tm = 0; tm < 2; ++tm) { \
                float2v h2_ = bb2_; \
                h2_ = __builtin_elementwise_fma((float2v){cxs[tm], cxs[tm]}, wx2_, h2_); \
                h2_ = __builtin_elementwise_fma((float2v){cys[tm], cys[tm]}, wy2_, h2_); \
                h2_ = __builtin_elementwise_fma((float2v){czs[tm], czs[tm]}, wz2_, h2_); \
                h2_ = __builtin_elementwise_max(h2_, (float2v){0.0f, 0.0f}); \
                sig2[tm] = __builtin_elementwise_fma(h2_, wsp_, sig2[tm]); \
                packed_[tm][p] = cvt_pk_bf16(h2_[0], h2_[1]); \
            } \
        } \
        uint4 v40_ = {packed_[0][0], packed_[0][1], packed_[0][2], packed_[0][3]}; \
        uint4 v41_ = {packed_[1][0], packed_[1][1], packed_[1][2], packed_[1][3]}; \
        short8 Ah0_ = __builtin_bit_cast(short8, v40_); \
        short8 Ah1_ = __builtin_bit_cast(short8, v41_); \
        acc[0][0] = __builtin_amdgcn_mfma_f32_16x16x32_bf16(Ah0_, B0, acc[0][0], 0, 0, 0); \
        acc[1][0] = __builtin_amdgcn_mfma_f32_16x16x32_bf16(Ah1_, B0, acc[1][0], 0, 0, 0); \
        acc[0][1] = __builtin_amdgcn_mfma_f32_16x16x32_bf16(Ah0_, B1, acc[0][1], 0, 0, 0); \
        acc[1][1] = __builtin_amdgcn_mfma_f32_16x16x32_bf16(Ah1_, B1, acc[1][1], 0, 0, 0); \
        acc[0][2] = __builtin_amdgcn_mfma_f32_16x16x32_bf16(Ah0_, B2, acc[0][2], 0, 0, 0); \
        acc[1][2] = __builtin_amdgcn_mfma_f32_16x16x32_bf16(Ah1_, B2, acc[1][2], 0, 0, 0); \
        acc[0][3] = __builtin_amdgcn_mfma_f32_16x16x32_bf16(Ah0_, B3, acc[0][3], 0, 0, 0); \
        acc[1][3] = __builtin_amdgcn_mfma_f32_16x16x32_bf16(Ah1_, B3, acc[1][3], 0, 0, 0); }

    #pragma unroll 1
    for (int ph = 0; ph < 2; ++ph) {
        // coords of the A-fragment rows for THIS pass (literal-indexed pair)
        float cxs[2], cys[2], czs[2];
        #pragma unroll
        for (int tm = 0; tm < 2; ++tm) {
            int src = (ph * 2 + tm) * 16 + c;
            cxs[tm] = __shfl(cx, src, 64);
            cys[tm] = __shfl(cy, src, 64);
            czs[tm] = __shfl(cz, src, 64);
        }

        floatx4 acc[2][4];
        #pragma unroll
        for (int tm = 0; tm < 2; ++tm) {
            { floatx4 v_; v_[0]=b2v0; v_[1]=b2v0; v_[2]=b2v0; v_[3]=b2v0; acc[tm][0]=v_; }
            { floatx4 v_; v_[0]=b2v1; v_[1]=b2v1; v_[2]=b2v1; v_[3]=b2v1; acc[tm][1]=v_; }
            { floatx4 v_; v_[0]=b2v2; v_[1]=b2v2; v_[2]=b2v2; v_[3]=b2v2; acc[tm][2]=v_; }
            { floatx4 v_; v_[0]=b2v3; v_[1]=b2v3; v_[2]=b2v3; v_[3]=b2v3; acc[tm][3]=v_; }
        }
        float2v sig2[2];
        sig2[0][0] = 0.0f; sig2[0][1] = 0.0f;
        sig2[1][0] = 0.0f; sig2[1][1] = 0.0f;

        // hand-unrolled kc pipeline: two named reg sets, loads one step ahead
        short8 bA0, bA1, bA2, bA3, bB0, bB1, bB2, bB3;
        LOADB(bA0, bA1, bA2, bA3, 0)
        KC_STEP(0, bA0, bA1, bA2, bA3, LOADB(bB0, bB1, bB2, bB3, 1))
        KC_STEP(1, bB0, bB1, bB2, bB3, LOADB(bA0, bA1, bA2, bA3, 2))
        KC_STEP(2, bA0, bA1, bA2, bA3, LOADB(bB0, bB1, bB2, bB3, 3))
        KC_STEP(3, bB0, bB1, bB2, bB3, )

        // ph==1 epilogue (wave 0) overwrites the w1p/ws2 alias region (rows
        // 32..63): all waves' kc-loop reads must complete first.
        if (ph == 1) __syncthreads();

        // phase C for this pass: feat rows -> fh, sigma partials collapse
        #pragma unroll
        for (int tm = 0; tm < 2; ++tm)
            #pragma unroll
            for (int tn = 0; tn < 4; ++tn)
                #pragma unroll
                for (int pr = 0; pr < 2; ++pr) {
                    uint32_t u = cvt_pk_bf16(acc[tm][tn][2 * pr], acc[tm][tn][2 * pr + 1]);
                    int m0 = mbase + (ph * 2 + tm) * 16 + q * 4 + 2 * pr;
                    int i0 = m0 * 64 + c + (((tn * 2) ^ (m0 & 7)) << 3);
                    fh[i0]       = (unsigned short)u;
                    fh[i0 + d01] = (unsigned short)(u >> 16);
                }
        {
            float s0 = sig2[0][0] + sig2[0][1];
            s0 += __shfl_xor(s0, 16);
            s0 += __shfl_xor(s0, 32);
            float s1 = sig2[1][0] + sig2[1][1];
            s1 += __shfl_xor(s1, 16);
            s1 += __shfl_xor(s1, 32);
            if (ph == 0) { sgv[0] = s0; sgv[1] = s1; }   // wave-uniform branch,
            else         { sgv[2] = s0; sgv[3] = s1; }   // literal indices
        }
    }
#undef KC_STEP
#undef LOADB

    // ------- per-lane sigma: sgv[] is q-broadcast; own row = lane -> sgv[q] --
    float av;
    {
        float s01  = (q & 1) ? sgv[1] : sgv[0];
        float s23  = (q & 1) ? sgv[3] : sgv[2];
        float sa = ((q & 2) ? s23 : s01) + b2s;
        float sg = maskA ? (fmaxf(sa, 0.0f) + __logf(1.0f + __expf(-fabsf(sa)))) : 0.0f;
        av = -sg * dist;
    }

    // ---------------- transmittance scan, part 1 (intra-wave) ----------------
    float v = av;
    #pragma unroll
    for (int off = 1; off < 64; off <<= 1) {
        float u2 = __shfl_up(v, off);
        if (lane >= off) v += u2;
    }
    // slot-write NOW; the barrier + dependent read happen AFTER phase D, so
    // the global round-trip hides under the rgb-hidden GEMM.
    if (lane == 63 && wv < 3) out[ray * 3 + wv] = v;

    // hd[] uniform loads: latency hides under phase D's first pass
    float hd[4];
    #pragma unroll
    for (int tn = 0; tn < 4; ++tn) {
        int n = tn * 16 + c;
        hd[tn] = r_b1[n] + dxv * r_w1[64 * 64 + n] + dyv * r_w1[65 * 64 + n] + dzv * r_w1[66 * 64 + n];
    }

    // ---------------- Phase D: rgb-hidden GEMM, two tm-passes ----------------
    const short8* __restrict__ rw8 = (const short8*)(ws + WS_RW1);

    #pragma unroll 1
    for (int ph = 0; ph < 2; ++ph) {
        // bulk preload all 8 B-frags (global, L2-hot) before LDS reads + MFMA
        short8 rb[2][4];
        #pragma unroll
        for (int ks = 0; ks < 2; ++ks)
            #pragma unroll
            for (int tn = 0; tn < 4; ++tn)
                rb[ks][tn] = rw8[(ks * 4 + tn) * 64 + lane];

        // pass-0 epilogue writes rows mbase+0..31; pass-1 afr reads rows
        // mbase+32..63 -- disjoint, wave-private: no barrier needed.
        short8 afr[2][2];
        #pragma unroll
        for (int tm = 0; tm < 2; ++tm)
            #pragma unroll
            for (int ks = 0; ks < 2; ++ks) {
                int m = mbase + (ph * 2 + tm) * 16 + c;
                int gl = ks * 4 + q;
                afr[tm][ks] = *(const short8*)&fh[m * 64 + ((gl ^ (m & 7)) << 3)];
            }

        floatx4 acc[2][4];
        #pragma unroll
        for (int tm = 0; tm < 2; ++tm)
            #pragma unroll
            for (int tn = 0; tn < 4; ++tn) {
                floatx4 z; z[0] = 0.0f; z[1] = 0.0f; z[2] = 0.0f; z[3] = 0.0f;
                acc[tm][tn] = z;
            }
        #pragma unroll
        for (int ks = 0; ks < 2; ++ks)
            #pragma unroll
            for (int tn = 0; tn < 4; ++tn)
                #pragma unroll
                for (int tm = 0; tm < 2; ++tm)
                    acc[tm][tn] = __builtin_amdgcn_mfma_f32_16x16x32_bf16(afr[tm][ks], rb[ks][tn], acc[tm][tn], 0, 0, 0);

        __builtin_amdgcn_wave_barrier();
        #pragma unroll
        for (int tm = 0; tm < 2; ++tm)
            #pragma unroll
            for (int tn = 0; tn < 4; ++tn)
                #pragma unroll
                for (int pr = 0; pr < 2; ++pr) {
                    float2v a2 = {acc[tm][tn][2 * pr], acc[tm][tn][2 * pr + 1]};
                    a2 = a2 + (float2v){hd[tn], hd[tn]};
                    a2 = __builtin_elementwise_max(a2, (float2v){0.0f, 0.0f});
                    uint32_t u = cvt_pk_bf16(a2[0], a2[1]);
                    int m0 = mbase + (ph * 2 + tm) * 16 + q * 4 + 2 * pr;
                    int i0 = m0 * 64 + c + (((tn * 2) ^ (m0 & 7)) << 3);
                    fh[i0]       = (unsigned short)u;
                    fh[i0 + d01] = (unsigned short)(u >> 16);
                }
    }

    // ---------------- scan part 2: cross-wave prefix (slot read) -------------
    __syncthreads();   // slot writes visible; also orders phase-D fh writes
    float sw0 = out[ray * 3 + 0];
    float sw1 = out[ray * 3 + 1];
    float sw2 = out[ray * 3 + 2];
    float basev = ((wv > 0) ? sw0 : 0.0f) + ((wv > 1) ? sw1 : 0.0f)
                + ((wv > 2) ? sw2 : 0.0f);
    float excl = __shfl_up(v, 1);
    if (lane == 0) excl = 0.0f;
    float cum    = basev + excl;
    float trans  = __expf(cum);
    float weight = trans * (1.0f - __expf(av));
    bool  mask2  = maskA && (trans > 1e-4f);

    // ---------------- Phase E: final 64->3 via transposed MFMA ---------------
    float wm = mask2 ? weight : 0.0f;
    // weights for rows tn*16+c via wave shuffle (all lanes execute: sources active)
    float wgt[4];
    #pragma unroll
    for (int tn = 0; tn < 4; ++tn) wgt[tn] = __shfl(wm, tn * 16 + c, 64);

    const unsigned short* __restrict__ w2eP = (const unsigned short*)(ws + WS_W2E);
    short8 w2f[2];
    w2f[0] = *(const short8*)(w2eP + (0 * 64 + lane) * 8);
    w2f[1] = *(const short8*)(w2eP + (1 * 64 + lane) * 8);

    floatx4 eacc[4];
    #pragma unroll
    for (int tn = 0; tn < 4; ++tn) {
        floatx4 z; z[0] = 0.0f; z[1] = 0.0f; z[2] = 0.0f; z[3] = 0.0f;
        eacc[tn] = z;
    }
    #pragma unroll
    for (int kf = 0; kf < 2; ++kf)
        #pragma unroll
        for (int tn = 0; tn < 4; ++tn) {
            int m = mbase + tn * 16 + c;
            int gl = kf * 4 + q;
            short8 hb = *(const short8*)&fh[m * 64 + ((gl ^ (m & 7)) << 3)];
            eacc[tn] = __builtin_amdgcn_mfma_f32_16x16x32_bf16(w2f[kf], hb, eacc[tn], 0, 0, 0);
        }

    float r = 0.0f, g = 0.0f, b = 0.0f;
    if (q == 0) {
        float rb0 = r_b2[0], rb1 = r_b2[1], rb2v = r_b2[2];
        #pragma unroll
        for (int tn = 0; tn < 4; ++tn) {
            float wgtv = wgt[tn];
            r += wgtv / (1.0f + __expf(-(eacc[tn][0] + rb0)));
            g += wgtv / (1.0f + __expf(-(eacc[tn][1] + rb1)));
            b += wgtv / (1.0f + __expf(-(eacc[tn][2] + rb2v)));
        }
    }
    #pragma unroll
    for (int off = 8; off > 0; off >>= 1) {
        r += __shfl_xor(r, off);
        g += __shfl_xor(g, off);
        b += __shfl_xor(b, off);
    }
    // cross-wave partials through each wave's own (now dead) fh region
    if (lane == 0) {
        float* pp = (float*)fhB + wv * 2048;   // byte offset wv*8192
        pp[0] = r; pp[1] = g; pp[2] = b;
    }
    __syncthreads();
    if (tid == 0) {
        float* pf = (float*)fhB;
        out[ray * 3 + 0] = pf[0] + pf[2048] + pf[4096] + pf[6144];
        out[ray * 3 + 1] = pf[1] + pf[2049] + pf[4097] + pf[6145];
        out[ray * 3 + 2] = pf[2] + pf[2050] + pf[4098] + pf[6146];
    }
}

extern "C" void kernel_launch(void* const* d_in, const int* in_sizes, int n_in,
                              void* d_out, int out_size, void* d_ws, size_t ws_size,
                              hipStream_t stream) {
    const int n_rays = in_sizes[0] / 3;   // 4096
    nerf_prep<<<1, 256, 0, stream>>>(
        (const float*)d_in[3], (const float*)d_in[4], (const float*)d_in[5],
        (const float*)d_in[6], (const float*)d_in[7], (const float*)d_in[8],
        (const float*)d_in[9], (const float*)d_in[11], (unsigned char*)d_ws);
    nerf_mfma<<<n_rays, 256, 0, stream>>>(
        (const float*)d_in[0],  (const float*)d_in[1],  (const float*)d_in[2],
        (const float*)d_in[6],  (const float*)d_in[9],  (const float*)d_in[10],
        (const float*)d_in[12],
        (const unsigned char*)d_ws, (float*)d_out);
}

// Round 6
// 169.174 us; speedup vs baseline: 2.1443x; 2.1443x over previous
//
#include <hip/hip_runtime.h>
#include <hip/hip_bf16.h>
#include <math.h>
#include <stdint.h>

#define S    256
#define GN   128

typedef __attribute__((ext_vector_type(8))) short  short8;   // 8 bf16
typedef __attribute__((ext_vector_type(4))) float  floatx4;  // MFMA C/D
typedef __attribute__((ext_vector_type(2))) float  float2v;  // v_pk_*_f32 pair

// workspace layout (bytes)
#define WS_BHI 0          // ushort[4*4*64*8] = 16384 B  (f_w2 bf16, frag order)
#define WS_RW1 16384      // ushort[2*4*64*8] =  8192 B  (r_w1 bf16, frag order)
#define WS_B2S 24576      // float  (b2.s_w + s_b)
#define WS_WS2 24592      // float[128]  (W2 @ s_w, fp32)
#define WS_W1P 25104      // float[64*8] pair-interleaved layer-1 = 2048 B
#define WS_W2E 27152      // ushort[2*64*8] = 2048 B (r_w2^T bf16, A-frag order)

__device__ __forceinline__ unsigned short bf16_rtne(float f) {
    uint32_t u = __builtin_bit_cast(uint32_t, f);
    uint32_t r = (u + 0x7fffu + ((u >> 16) & 1u)) >> 16;
    return (unsigned short)r;
}
__device__ __forceinline__ uint32_t cvt_pk_bf16(float a, float b) {
    float2 hh; hh.x = a; hh.y = b;
    __hip_bfloat162 pk = __float22bfloat162_rn(hh);   // v_cvt_pk_bf16_f32
    uint32_t u; __builtin_memcpy(&u, &pk, 4);
    return u;
}

// ---------- pre-pack kernel: weights -> bf16 in MFMA fragment order ----------
__global__ __launch_bounds__(256)
void nerf_prep(const float* __restrict__ f_w1, const float* __restrict__ f_b1,
               const float* __restrict__ f_w2, const float* __restrict__ f_b2,
               const float* __restrict__ s_w,  const float* __restrict__ s_b,
               const float* __restrict__ r_w1, const float* __restrict__ r_w2,
               unsigned char* __restrict__ ws)
{
    const int tid = threadIdx.x;
    if (tid < 128) {                       // ws2 = W2 @ s_w  (fp32) -> global
        float acc = 0.0f;
        for (int n = 0; n < 64; ++n) acc += f_w2[tid * 64 + n] * s_w[n];
        ((float*)(ws + WS_WS2))[tid] = acc;
    } else if (tid == 128) {               // b2s = b2 . s_w + s_b
        float acc = s_b[0];
        for (int n = 0; n < 64; ++n) acc += f_b2[n] * s_w[n];
        *(float*)(ws + WS_B2S) = acc;
    }
    // layer-1 pair-interleaved pack: pair pp covers k=2pp,2pp+1:
    //   {wx0,wx1, wy0,wy1, wz0,wz1, b0,b1}  (aligned float2 pairs for v_pk_fma)
    {
        float* w1pk = (float*)(ws + WS_W1P);
        for (int pp = tid; pp < 64; pp += 256) {
            int k0 = 2 * pp, k1 = 2 * pp + 1;
            w1pk[pp * 8 + 0] = f_w1[k0];       w1pk[pp * 8 + 1] = f_w1[k1];
            w1pk[pp * 8 + 2] = f_w1[128 + k0]; w1pk[pp * 8 + 3] = f_w1[128 + k1];
            w1pk[pp * 8 + 4] = f_w1[256 + k0]; w1pk[pp * 8 + 5] = f_w1[256 + k1];
            w1pk[pp * 8 + 6] = f_b1[k0];       w1pk[pp * 8 + 7] = f_b1[k1];
        }
    }

    unsigned short* bhi = (unsigned short*)(ws + WS_BHI);
    for (int i = tid; i < 8192; i += 256) {
        int j = i & 7, L = (i >> 3) & 63, g = i >> 9;   // g = kc*4 + tn
        int tn = g & 3, kc = g >> 2;
        int q = L >> 4, cc = L & 15;
        int k = kc * 32 + q * 8 + j;
        bhi[i] = bf16_rtne(f_w2[k * 64 + tn * 16 + cc]);
    }
    unsigned short* rw = (unsigned short*)(ws + WS_RW1);
    for (int i = tid; i < 4096; i += 256) {
        int j = i & 7, L = (i >> 3) & 63, g = i >> 9;   // g = ks*4 + tn
        int tn = g & 3, ks = g >> 2;
        int q = L >> 4, cc = L & 15;
        int k = ks * 32 + q * 8 + j;
        rw[i] = bf16_rtne(r_w1[k * 64 + tn * 16 + cc]);
    }
    // r_w2^T in A-fragment order for the phase-E MFMA:
    // A[row=out-channel][k=hidden]; rows 3..15 zero.
    unsigned short* w2e = (unsigned short*)(ws + WS_W2E);
    for (int i = tid; i < 1024; i += 256) {
        int j = i & 7, L = (i >> 3) & 63, kf = i >> 9;
        int q = L >> 4, ch = L & 15;
        int k = kf * 32 + q * 8 + j;
        w2e[i] = (ch < 3) ? bf16_rtne(r_w2[k * 3 + ch]) : (unsigned short)0;
    }
}

// ---------------------------- main kernel -----------------------------------
// R23 = R21 verbatim (the verified 88 us kernel) + ONE register-neutral edit.
// R22 post-mortem: the hand-unrolled LOADB/KC_STEP prefetch pipeline held
// +32 VGPR of B-frags live across the ~90-op h-compute -> allocator spilled
// the pipeline regs themselves -> 668 MB scratch writes, dur 284 us. Third
// spill event (R18, R20, R22): ANY edit extending vector live ranges across
// a long region trips spill pathology at this kernel's ~60-VGPR operating
// point. Prefetch-depth lever is CLOSED on this structure.
// The one surviving R22 edit (register-neutral by construction):
//   scan straddle -- slot-write stays before phase D; the barrier + slot-read
//   + weight computation move AFTER phase D. Phase D has no dependence on the
//   scan result (weight only feeds phase E), so the global L2 round-trip
//   (~400-600 cyc, previously a full-block serial stall) hides under phase
//   D's MFMA work. Live ranges across phase D: {v, av, maskA} instead of
//   {weight, mask2} -- net ~+1 reg.
// Tripwire: WRITE_SIZE ~1.3 MB / FETCH ~15 MB (spill detector).
__global__ __launch_bounds__(256, 4)
void nerf_mfma(const float* __restrict__ rays_o,
               const float* __restrict__ rays_d,
               const float* __restrict__ grid,
               const float* __restrict__ f_b2,
               const float* __restrict__ r_w1,
               const float* __restrict__ r_b1,
               const float* __restrict__ r_b2,
               const unsigned char* __restrict__ ws,
               float* __restrict__ out)
{
    // fh: bf16 [256 rows][64], XOR-swizzled in 8-ushort groups: conflict-free
    // b128. 32768 B exactly = the ONLY LDS object.
    __shared__ __align__(16) unsigned short fh[256 * 64];
    unsigned char* fhB = (unsigned char*)fh;

    const int tid   = threadIdx.x;
    const int ray   = blockIdx.x;
    const int lane  = tid & 63;
    const int wv    = tid >> 6;
    const int q     = lane >> 4;
    const int c     = lane & 15;
    const int mbase = wv * 64;
    const int d01   = 72 - ((c >> 3) << 4);   // i1 - i0 in the epilogue swizzle

    // stage layer-1 pack (2 KB) + ws2 (512 B) into fh rows 32..63 region
    if (tid < 128) {
        ((float4*)(fhB + 4096))[tid] = ((const float4*)(ws + WS_W1P))[tid];
        ((float*)(fhB + 6144))[tid]  = ((const float*)(ws + WS_WS2))[tid];
    }

    // ---------------- Phase A: geometry + grid sample (thread = sample) ------
    const float stop = 1.0f - 1.0f / (float)(S + 2);
    const float step = stop / (float)S;
    float u0 = (float)tid * step;
    float u1 = (float)(tid + 1) * step;
    float t    = (u0 < 0.5f) ? 2.0f * u0 : 1.0f / (2.0f - 2.0f * u0);
    float tn_  = (u1 < 0.5f) ? 2.0f * u1 : 1.0f / (2.0f - 2.0f * u1);
    float dist = tn_ - t;

    float ox = rays_o[ray * 3 + 0], oy = rays_o[ray * 3 + 1], oz = rays_o[ray * 3 + 2];
    float dxv = rays_d[ray * 3 + 0], dyv = rays_d[ray * 3 + 1], dzv = rays_d[ray * 3 + 2];

    float px = ox + dxv * t, py = oy + dyv * t, pz = oz + dzv * t;
    float nrm = sqrtf(px * px + py * py + pz * pz);
    float scale = (nrm <= 1.0f) ? 0.5f : (2.0f - 1.0f / nrm) / nrm * 0.5f;
    float cx = px * scale, cy = py * scale, cz = pz * scale;

    float ix = ((cx + 1.0f) * (float)GN - 1.0f) * 0.5f;
    float iy = ((cy + 1.0f) * (float)GN - 1.0f) * 0.5f;
    float iz = ((cz + 1.0f) * (float)GN - 1.0f) * 0.5f;
    float fx0 = floorf(ix), fy0 = floorf(iy), fz0 = floorf(iz);
    float fx = ix - fx0, fy = iy - fy0, fz = iz - fz0;
    int x0 = (int)fx0, y0 = (int)fy0, z0 = (int)fz0;
    int x1 = x0 + 1, y1 = y0 + 1, z1 = z0 + 1;

    // contracted coords strictly inside [-1,1] -> x0 in [-1,127], x1 in [0,128].
    // Only boundary taps can be invalid: zero the per-axis weight, clamp the
    // index. 0*g == 0 exactly; product order (wx*wy)*wz matches branchy version.
    float wxv[2], wyv[2], wzv[2];
    wxv[0] = (x0 >= 0) ? (1.0f - fx) : 0.0f;  wxv[1] = (x1 < GN) ? fx : 0.0f;
    wyv[0] = (y0 >= 0) ? (1.0f - fy) : 0.0f;  wyv[1] = (y1 < GN) ? fy : 0.0f;
    wzv[0] = (z0 >= 0) ? (1.0f - fz) : 0.0f;  wzv[1] = (z1 < GN) ? fz : 0.0f;
    int xc[2], yb[2], zb[2];
    xc[0] = (x0 < 0) ? 0 : x0;              xc[1] = (x1 > GN - 1) ? GN - 1 : x1;
    yb[0] = ((y0 < 0) ? 0 : y0) * GN;       yb[1] = ((y1 > GN - 1) ? GN - 1 : y1) * GN;
    zb[0] = ((z0 < 0) ? 0 : z0) * (GN*GN);  zb[1] = ((z1 > GN - 1) ? GN - 1 : z1) * (GN*GN);

    float occ = 0.0f;
    #pragma unroll
    for (int dzc = 0; dzc < 2; ++dzc)
    #pragma unroll
    for (int dyc = 0; dyc < 2; ++dyc)
    #pragma unroll
    for (int dxc = 0; dxc < 2; ++dxc) {
        float w = (wxv[dxc] * wyv[dyc]) * wzv[dzc];
        occ += w * grid[zb[dzc] + yb[dyc] + xc[dxc]];
    }
    bool maskA = occ > 0.01f;

    __syncthreads();   // w1p / ws2 staged into fh region

    // ------- Phase B+C: feat GEMM in two tm-passes (acc[2][4] = 32 AGPR) -----
    const unsigned short* __restrict__ bhiP = (const unsigned short*)(ws + WS_BHI);
    float sgv[4] = {0.0f, 0.0f, 0.0f, 0.0f};   // all reads/writes literal-indexed

    #pragma unroll 1
    for (int ph = 0; ph < 2; ++ph) {
        // coords of the A-fragment rows for THIS pass (literal-indexed pair;
        // ph only appears in the shuffle source lane -> no scratch)
        float cxs[2], cys[2], czs[2];
        #pragma unroll
        for (int tm = 0; tm < 2; ++tm) {
            int src = (ph * 2 + tm) * 16 + c;
            cxs[tm] = __shfl(cx, src, 64);
            cys[tm] = __shfl(cy, src, 64);
            czs[tm] = __shfl(cz, src, 64);
        }

        floatx4 acc[2][4];
        {
            float b2v[4];
            #pragma unroll
            for (int tn = 0; tn < 4; ++tn) b2v[tn] = f_b2[tn * 16 + c];
            #pragma unroll
            for (int tm = 0; tm < 2; ++tm)
                #pragma unroll
                for (int tn = 0; tn < 4; ++tn) {
                    floatx4 v; v[0] = b2v[tn]; v[1] = b2v[tn]; v[2] = b2v[tn]; v[3] = b2v[tn];
                    acc[tm][tn] = v;
                }
        }
        float2v sig2[2];
        sig2[0][0] = 0.0f; sig2[0][1] = 0.0f;
        sig2[1][0] = 0.0f; sig2[1][1] = 0.0f;

        #pragma unroll 2
        for (int kc = 0; kc < 4; ++kc) {
            const int k0  = kc * 32 + q * 8;
            const int pp0 = kc * 16 + q * 4;
            const float4* w1q4 = (const float4*)(fhB + 4096 + pp0 * 32);
            float ws2r[8];
            *(float4*)(ws2r)     = *(const float4*)(fhB + 6144 + k0 * 4);
            *(float4*)(ws2r + 4) = *(const float4*)(fhB + 6144 + k0 * 4 + 16);

            uint32_t packed[2][4];
            #pragma unroll
            for (int p = 0; p < 4; ++p) {
                float4 q0 = w1q4[2 * p];         // {wx0,wx1, wy0,wy1}
                float4 q1 = w1q4[2 * p + 1];     // {wz0,wz1, b0, b1}
                float2v wx2 = {q0.x, q0.y};
                float2v wy2 = {q0.z, q0.w};
                float2v wz2 = {q1.x, q1.y};
                float2v bb2 = {q1.z, q1.w};
                float2v wsp = {ws2r[2 * p], ws2r[2 * p + 1]};
                #pragma unroll
                for (int tm = 0; tm < 2; ++tm) {
                    float2v h2 = bb2;
                    h2 = __builtin_elementwise_fma((float2v){cxs[tm], cxs[tm]}, wx2, h2);
                    h2 = __builtin_elementwise_fma((float2v){cys[tm], cys[tm]}, wy2, h2);
                    h2 = __builtin_elementwise_fma((float2v){czs[tm], czs[tm]}, wz2, h2);
                    h2 = __builtin_elementwise_max(h2, (float2v){0.0f, 0.0f});
                    sig2[tm] = __builtin_elementwise_fma(h2, wsp, sig2[tm]);
                    packed[tm][p] = cvt_pk_bf16(h2[0], h2[1]);
                }
            }
            short8 Ah[2];
            #pragma unroll
            for (int tm = 0; tm < 2; ++tm) {
                uint4 v4 = {packed[tm][0], packed[tm][1], packed[tm][2], packed[tm][3]};
                Ah[tm] = __builtin_bit_cast(short8, v4);
            }
            const int bbase = (kc * 4) * 512 + lane * 8;
            #pragma unroll
            for (int tn = 0; tn < 4; ++tn) {
                short8 bh = *(const short8*)(bhiP + bbase + tn * 512);
                #pragma unroll
                for (int tm = 0; tm < 2; ++tm)
                    acc[tm][tn] = __builtin_amdgcn_mfma_f32_16x16x32_bf16(Ah[tm], bh, acc[tm][tn], 0, 0, 0);
            }
        }

        // ph==1 epilogue (wave 0) overwrites the w1p/ws2 alias region (rows
        // 32..63): all waves' kc-loop reads must complete first.
        if (ph == 1) __syncthreads();

        // phase C for this pass: feat rows -> fh, sigma partials collapse
        #pragma unroll
        for (int tm = 0; tm < 2; ++tm)
            #pragma unroll
            for (int tn = 0; tn < 4; ++tn)
                #pragma unroll
                for (int pr = 0; pr < 2; ++pr) {
                    uint32_t u = cvt_pk_bf16(acc[tm][tn][2 * pr], acc[tm][tn][2 * pr + 1]);
                    int m0 = mbase + (ph * 2 + tm) * 16 + q * 4 + 2 * pr;
                    int i0 = m0 * 64 + c + (((tn * 2) ^ (m0 & 7)) << 3);
                    fh[i0]       = (unsigned short)u;
                    fh[i0 + d01] = (unsigned short)(u >> 16);
                }
        {
            float s0 = sig2[0][0] + sig2[0][1];
            s0 += __shfl_xor(s0, 16);
            s0 += __shfl_xor(s0, 32);
            float s1 = sig2[1][0] + sig2[1][1];
            s1 += __shfl_xor(s1, 16);
            s1 += __shfl_xor(s1, 32);
            if (ph == 0) { sgv[0] = s0; sgv[1] = s1; }   // wave-uniform branch,
            else         { sgv[2] = s0; sgv[3] = s1; }   // literal indices
        }
    }

    // ------- per-lane sigma: sgv[] is q-broadcast; own row = lane -> sgv[q] --
    float av;
    {
        float b2s = *(const float*)(ws + WS_B2S);
        float s01  = (q & 1) ? sgv[1] : sgv[0];
        float s23  = (q & 1) ? sgv[3] : sgv[2];
        float sa = ((q & 2) ? s23 : s01) + b2s;
        float sg = maskA ? (fmaxf(sa, 0.0f) + __logf(1.0f + __expf(-fabsf(sa)))) : 0.0f;
        av = -sg * dist;
    }

    // hd[] uniform loads: latency hides under the scan below
    float hd[4];
    #pragma unroll
    for (int tn = 0; tn < 4; ++tn) {
        int n = tn * 16 + c;
        hd[tn] = r_b1[n] + dxv * r_w1[64 * 64 + n] + dyv * r_w1[65 * 64 + n] + dzv * r_w1[66 * 64 + n];
    }

    // ---------------- transmittance scan, part 1 (intra-wave) ----------------
    float v = av;
    #pragma unroll
    for (int off = 1; off < 64; off <<= 1) {
        float u2 = __shfl_up(v, off);
        if (lane >= off) v += u2;
    }
    // slot-write NOW; barrier + dependent read happen AFTER phase D, so the
    // global L2 round-trip hides under the rgb-hidden GEMM (phase D has no
    // dependence on the scan result -- weight only feeds phase E).
    if (lane == 63 && wv < 3) out[ray * 3 + wv] = v;

    // ---------------- Phase D: rgb-hidden GEMM, two tm-passes ----------------
    const unsigned short* __restrict__ rwP = (const unsigned short*)(ws + WS_RW1);

    #pragma unroll 1
    for (int ph = 0; ph < 2; ++ph) {
        // pass-0 epilogue writes rows mbase+0..31; pass-1 afr reads rows
        // mbase+32..63 -- disjoint, wave-private: no barrier needed.
        short8 afr[2][2];
        #pragma unroll
        for (int tm = 0; tm < 2; ++tm)
            #pragma unroll
            for (int ks = 0; ks < 2; ++ks) {
                int m = mbase + (ph * 2 + tm) * 16 + c;
                int gl = ks * 4 + q;
                afr[tm][ks] = *(const short8*)&fh[m * 64 + ((gl ^ (m & 7)) << 3)];
            }

        floatx4 acc[2][4];
        #pragma unroll
        for (int tm = 0; tm < 2; ++tm)
            #pragma unroll
            for (int tn = 0; tn < 4; ++tn) {
                floatx4 z; z[0] = 0.0f; z[1] = 0.0f; z[2] = 0.0f; z[3] = 0.0f;
                acc[tm][tn] = z;
            }
        #pragma unroll
        for (int ks = 0; ks < 2; ++ks)
            #pragma unroll
            for (int tn = 0; tn < 4; ++tn) {
                short8 rb = *(const short8*)(rwP + ((ks * 4 + tn) * 64 + lane) * 8);
                #pragma unroll
                for (int tm = 0; tm < 2; ++tm)
                    acc[tm][tn] = __builtin_amdgcn_mfma_f32_16x16x32_bf16(afr[tm][ks], rb, acc[tm][tn], 0, 0, 0);
            }

        __builtin_amdgcn_wave_barrier();
        #pragma unroll
        for (int tm = 0; tm < 2; ++tm)
            #pragma unroll
            for (int tn = 0; tn < 4; ++tn)
                #pragma unroll
                for (int pr = 0; pr < 2; ++pr) {
                    float2v a2 = {acc[tm][tn][2 * pr], acc[tm][tn][2 * pr + 1]};
                    a2 = a2 + (float2v){hd[tn], hd[tn]};
                    a2 = __builtin_elementwise_max(a2, (float2v){0.0f, 0.0f});
                    uint32_t u = cvt_pk_bf16(a2[0], a2[1]);
                    int m0 = mbase + (ph * 2 + tm) * 16 + q * 4 + 2 * pr;
                    int i0 = m0 * 64 + c + (((tn * 2) ^ (m0 & 7)) << 3);
                    fh[i0]       = (unsigned short)u;
                    fh[i0 + d01] = (unsigned short)(u >> 16);
                }
    }

    // ---------------- scan part 2: cross-wave prefix (slot read) -------------
    __syncthreads();   // slot writes visible to all waves
    float sw0 = out[ray * 3 + 0];
    float sw1 = out[ray * 3 + 1];
    float sw2 = out[ray * 3 + 2];
    float basev = ((wv > 0) ? sw0 : 0.0f) + ((wv > 1) ? sw1 : 0.0f)
                + ((wv > 2) ? sw2 : 0.0f);
    float excl = __shfl_up(v, 1);
    if (lane == 0) excl = 0.0f;
    float cum    = basev + excl;
    float trans  = __expf(cum);
    float weight = trans * (1.0f - __expf(av));
    bool  mask2  = maskA && (trans > 1e-4f);

    // ---------------- Phase E: final 64->3 via transposed MFMA ---------------
    float wm = mask2 ? weight : 0.0f;
    // weights for rows tn*16+c via wave shuffle (all lanes execute: sources active)
    float wgt[4];
    #pragma unroll
    for (int tn = 0; tn < 4; ++tn) wgt[tn] = __shfl(wm, tn * 16 + c, 64);

    const unsigned short* __restrict__ w2eP = (const unsigned short*)(ws + WS_W2E);
    short8 w2f[2];
    w2f[0] = *(const short8*)(w2eP + (0 * 64 + lane) * 8);
    w2f[1] = *(const short8*)(w2eP + (1 * 64 + lane) * 8);

    floatx4 eacc[4];
    #pragma unroll
    for (int tn = 0; tn < 4; ++tn) {
        floatx4 z; z[0] = 0.0f; z[1] = 0.0f; z[2] = 0.0f; z[3] = 0.0f;
        eacc[tn] = z;
    }
    #pragma unroll
    for (int kf = 0; kf < 2; ++kf)
        #pragma unroll
        for (int tn = 0; tn < 4; ++tn) {
            int m = mbase + tn * 16 + c;
            int gl = kf * 4 + q;
            short8 hb = *(const short8*)&fh[m * 64 + ((gl ^ (m & 7)) << 3)];
            eacc[tn] = __builtin_amdgcn_mfma_f32_16x16x32_bf16(w2f[kf], hb, eacc[tn], 0, 0, 0);
        }

    float r = 0.0f, g = 0.0f, b = 0.0f;
    if (q == 0) {
        float rb0 = r_b2[0], rb1 = r_b2[1], rb2v = r_b2[2];
        #pragma unroll
        for (int tn = 0; tn < 4; ++tn) {
            float wgtv = wgt[tn];
            r += wgtv / (1.0f + __expf(-(eacc[tn][0] + rb0)));
            g += wgtv / (1.0f + __expf(-(eacc[tn][1] + rb1)));
            b += wgtv / (1.0f + __expf(-(eacc[tn][2] + rb2v)));
        }
    }
    #pragma unroll
    for (int off = 8; off > 0; off >>= 1) {
        r += __shfl_xor(r, off);
        g += __shfl_xor(g, off);
        b += __shfl_xor(b, off);
    }
    // cross-wave partials through each wave's own (now dead) fh region
    if (lane == 0) {
        float* pp = (float*)fhB + wv * 2048;   // byte offset wv*8192
        pp[0] = r; pp[1] = g; pp[2] = b;
    }
    __syncthreads();
    if (tid == 0) {
        float* pf = (float*)fhB;
        out[ray * 3 + 0] = pf[0] + pf[2048] + pf[4096] + pf[6144];
        out[ray * 3 + 1] = pf[1] + pf[2049] + pf[4097] + pf[6145];
        out[ray * 3 + 2] = pf[2] + pf[2050] + pf[4098] + pf[6146];
    }
}

extern "C" void kernel_launch(void* const* d_in, const int* in_sizes, int n_in,
                              void* d_out, int out_size, void* d_ws, size_t ws_size,
                              hipStream_t stream) {
    const int n_rays = in_sizes[0] / 3;   // 4096
    nerf_prep<<<1, 256, 0, stream>>>(
        (const float*)d_in[3], (const float*)d_in[4], (const float*)d_in[5],
        (const float*)d_in[6], (const float*)d_in[7], (const float*)d_in[8],
        (const float*)d_in[9], (const float*)d_in[11], (unsigned char*)d_ws);
    nerf_mfma<<<n_rays, 256, 0, stream>>>(
        (const float*)d_in[0],  (const float*)d_in[1],  (const float*)d_in[2],
        (const float*)d_in[6],  (const float*)d_in[9],  (const float*)d_in[10],
        (const float*)d_in[12],
        (const unsigned char*)d_ws, (float*)d_out);
}

// Round 7
// 167.902 us; speedup vs baseline: 2.1605x; 1.0076x over previous
//
#include <hip/hip_runtime.h>
#include <hip/hip_bf16.h>
#include <math.h>
#include <stdint.h>

#define S    256
#define GN   128

typedef __attribute__((ext_vector_type(8))) short  short8;   // 8 bf16
typedef __attribute__((ext_vector_type(4))) float  floatx4;  // MFMA C/D
typedef __attribute__((ext_vector_type(2))) float  float2v;  // v_pk_*_f32 pair

// workspace layout (bytes)
#define WS_BHI 0          // ushort[4*4*64*8] = 16384 B  (f_w2 bf16, frag order)
#define WS_RW1 16384      // ushort[2*4*64*8] =  8192 B  (r_w1 bf16, frag order)
#define WS_B2S 24576      // float  (b2.s_w + s_b)
#define WS_WS2 24592      // float[128]  (W2 @ s_w, fp32)
#define WS_W1P 25104      // float[64*8] pair-interleaved layer-1 = 2048 B
#define WS_W2E 27152      // ushort[2*64*8] = 2048 B (r_w2^T bf16, A-frag order)

__device__ __forceinline__ unsigned short bf16_rtne(float f) {
    uint32_t u = __builtin_bit_cast(uint32_t, f);
    uint32_t r = (u + 0x7fffu + ((u >> 16) & 1u)) >> 16;
    return (unsigned short)r;
}
__device__ __forceinline__ uint32_t cvt_pk_bf16(float a, float b) {
    float2 hh; hh.x = a; hh.y = b;
    __hip_bfloat162 pk = __float22bfloat162_rn(hh);   // v_cvt_pk_bf16_f32
    uint32_t u; __builtin_memcpy(&u, &pk, 4);
    return u;
}

// ---------- pre-pack kernel: weights -> bf16 in MFMA fragment order ----------
__global__ __launch_bounds__(256)
void nerf_prep(const float* __restrict__ f_w1, const float* __restrict__ f_b1,
               const float* __restrict__ f_w2, const float* __restrict__ f_b2,
               const float* __restrict__ s_w,  const float* __restrict__ s_b,
               const float* __restrict__ r_w1, const float* __restrict__ r_w2,
               unsigned char* __restrict__ ws)
{
    const int tid = threadIdx.x;
    if (tid < 128) {                       // ws2 = W2 @ s_w  (fp32) -> global
        float acc = 0.0f;
        for (int n = 0; n < 64; ++n) acc += f_w2[tid * 64 + n] * s_w[n];
        ((float*)(ws + WS_WS2))[tid] = acc;
    } else if (tid == 128) {               // b2s = b2 . s_w + s_b
        float acc = s_b[0];
        for (int n = 0; n < 64; ++n) acc += f_b2[n] * s_w[n];
        *(float*)(ws + WS_B2S) = acc;
    }
    // layer-1 pair-interleaved pack: pair pp covers k=2pp,2pp+1:
    //   {wx0,wx1, wy0,wy1, wz0,wz1, b0,b1}  (aligned float2 pairs for v_pk_fma)
    {
        float* w1pk = (float*)(ws + WS_W1P);
        for (int pp = tid; pp < 64; pp += 256) {
            int k0 = 2 * pp, k1 = 2 * pp + 1;
            w1pk[pp * 8 + 0] = f_w1[k0];       w1pk[pp * 8 + 1] = f_w1[k1];
            w1pk[pp * 8 + 2] = f_w1[128 + k0]; w1pk[pp * 8 + 3] = f_w1[128 + k1];
            w1pk[pp * 8 + 4] = f_w1[256 + k0]; w1pk[pp * 8 + 5] = f_w1[256 + k1];
            w1pk[pp * 8 + 6] = f_b1[k0];       w1pk[pp * 8 + 7] = f_b1[k1];
        }
    }

    unsigned short* bhi = (unsigned short*)(ws + WS_BHI);
    for (int i = tid; i < 8192; i += 256) {
        int j = i & 7, L = (i >> 3) & 63, g = i >> 9;   // g = kc*4 + tn
        int tn = g & 3, kc = g >> 2;
        int q = L >> 4, cc = L & 15;
        int k = kc * 32 + q * 8 + j;
        bhi[i] = bf16_rtne(f_w2[k * 64 + tn * 16 + cc]);
    }
    unsigned short* rw = (unsigned short*)(ws + WS_RW1);
    for (int i = tid; i < 4096; i += 256) {
        int j = i & 7, L = (i >> 3) & 63, g = i >> 9;   // g = ks*4 + tn
        int tn = g & 3, ks = g >> 2;
        int q = L >> 4, cc = L & 15;
        int k = ks * 32 + q * 8 + j;
        rw[i] = bf16_rtne(r_w1[k * 64 + tn * 16 + cc]);
    }
    // r_w2^T in A-fragment order for the phase-E MFMA:
    // A[row=out-channel][k=hidden]; rows 3..15 zero.
    unsigned short* w2e = (unsigned short*)(ws + WS_W2E);
    for (int i = tid; i < 1024; i += 256) {
        int j = i & 7, L = (i >> 3) & 63, kf = i >> 9;
        int q = L >> 4, ch = L & 15;
        int k = kf * 32 + q * 8 + j;
        w2e[i] = (ch < 3) ? bf16_rtne(r_w2[k * 3 + ch]) : (unsigned short)0;
    }
}

// ---------------------------- main kernel -----------------------------------
// R24 = R23 + bhi(kc=0..2) staged into pristine fh regions via
// __builtin_amdgcn_global_load_lds -- ZERO LDS growth, ZERO new vector live
// ranges (global_load_lds has no VGPR destination; anti-spill constraint from
// R18/R20/R22 honored by construction).
// Lifetime proof: the `if(ph==1) __syncthreads()` orders ALL waves' kc-loop
// reads (both ph passes) before ANY ph1-epilogue fh write. Hence the ph1 rows
// of waves 1..3 -- fh bytes 12288..16383 / 20480..24575 / 28672..32767, 12 KB
// -- are pristine from kernel start until exactly when bhi dies. kc=0..2's
// 12 chunks of 1 KB are staged there (3 chunks per wave, wave-uniform LDS
// base + lane*16 linear dest, the global_load_lds contract); the post-phase-A
// __syncthreads drains vmcnt before any read. kc=3 stays a global L2 read.
// Phase-B B-frag loads: 24 of 32 become conflict-free lane-contiguous
// ds_read_b128 (~60cyc) instead of L2 (~200-300cyc).
// Tripwire: WRITE_SIZE ~1.3 MB / FETCH ~15 MB (spill detector).
__global__ __launch_bounds__(256, 4)
void nerf_mfma(const float* __restrict__ rays_o,
               const float* __restrict__ rays_d,
               const float* __restrict__ grid,
               const float* __restrict__ f_b2,
               const float* __restrict__ r_w1,
               const float* __restrict__ r_b1,
               const float* __restrict__ r_b2,
               const unsigned char* __restrict__ ws,
               float* __restrict__ out)
{
    // fh: bf16 [256 rows][64], XOR-swizzled in 8-ushort groups: conflict-free
    // b128. 32768 B exactly = the ONLY LDS object.
    __shared__ __align__(16) unsigned short fh[256 * 64];
    unsigned char* fhB = (unsigned char*)fh;

    const int tid   = threadIdx.x;
    const int ray   = blockIdx.x;
    const int lane  = tid & 63;
    const int wv    = tid >> 6;
    const int q     = lane >> 4;
    const int c     = lane & 15;
    const int mbase = wv * 64;
    const int d01   = 72 - ((c >> 3) << 4);   // i1 - i0 in the epilogue swizzle

    // ---- async-stage bhi kc=0..2 into the pristine ph1 regions (12 chunks
    // of 1 KB; 3 per wave; dest is wave-uniform base + lane*16, linear) ----
    #pragma unroll
    for (int i = 0; i < 3; ++i) {
        int g   = wv * 3 + i;                              // chunk = kc*4+tn
        int dst = 12288 + (g >> 2) * 8192 + (g & 3) * 1024;
        __builtin_amdgcn_global_load_lds(
            (const __attribute__((address_space(1))) unsigned int*)
                (const void*)(ws + WS_BHI + g * 1024 + lane * 16),
            (__attribute__((address_space(3))) unsigned int*)
                (void*)(fhB + dst),
            16, 0, 0);
    }

    // stage layer-1 pack (2 KB) + ws2 (512 B) into fh rows 32..51 region
    if (tid < 128) {
        ((float4*)(fhB + 4096))[tid] = ((const float4*)(ws + WS_W1P))[tid];
        ((float*)(fhB + 6144))[tid]  = ((const float*)(ws + WS_WS2))[tid];
    }

    // ---------------- Phase A: geometry + grid sample (thread = sample) ------
    const float stop = 1.0f - 1.0f / (float)(S + 2);
    const float step = stop / (float)S;
    float u0 = (float)tid * step;
    float u1 = (float)(tid + 1) * step;
    float t    = (u0 < 0.5f) ? 2.0f * u0 : 1.0f / (2.0f - 2.0f * u0);
    float tn_  = (u1 < 0.5f) ? 2.0f * u1 : 1.0f / (2.0f - 2.0f * u1);
    float dist = tn_ - t;

    float ox = rays_o[ray * 3 + 0], oy = rays_o[ray * 3 + 1], oz = rays_o[ray * 3 + 2];
    float dxv = rays_d[ray * 3 + 0], dyv = rays_d[ray * 3 + 1], dzv = rays_d[ray * 3 + 2];

    float px = ox + dxv * t, py = oy + dyv * t, pz = oz + dzv * t;
    float nrm = sqrtf(px * px + py * py + pz * pz);
    float scale = (nrm <= 1.0f) ? 0.5f : (2.0f - 1.0f / nrm) / nrm * 0.5f;
    float cx = px * scale, cy = py * scale, cz = pz * scale;

    float ix = ((cx + 1.0f) * (float)GN - 1.0f) * 0.5f;
    float iy = ((cy + 1.0f) * (float)GN - 1.0f) * 0.5f;
    float iz = ((cz + 1.0f) * (float)GN - 1.0f) * 0.5f;
    float fx0 = floorf(ix), fy0 = floorf(iy), fz0 = floorf(iz);
    float fx = ix - fx0, fy = iy - fy0, fz = iz - fz0;
    int x0 = (int)fx0, y0 = (int)fy0, z0 = (int)fz0;
    int x1 = x0 + 1, y1 = y0 + 1, z1 = z0 + 1;

    // contracted coords strictly inside [-1,1] -> x0 in [-1,127], x1 in [0,128].
    // Only boundary taps can be invalid: zero the per-axis weight, clamp the
    // index. 0*g == 0 exactly; product order (wx*wy)*wz matches branchy version.
    float wxv[2], wyv[2], wzv[2];
    wxv[0] = (x0 >= 0) ? (1.0f - fx) : 0.0f;  wxv[1] = (x1 < GN) ? fx : 0.0f;
    wyv[0] = (y0 >= 0) ? (1.0f - fy) : 0.0f;  wyv[1] = (y1 < GN) ? fy : 0.0f;
    wzv[0] = (z0 >= 0) ? (1.0f - fz) : 0.0f;  wzv[1] = (z1 < GN) ? fz : 0.0f;
    int xc[2], yb[2], zb[2];
    xc[0] = (x0 < 0) ? 0 : x0;              xc[1] = (x1 > GN - 1) ? GN - 1 : x1;
    yb[0] = ((y0 < 0) ? 0 : y0) * GN;       yb[1] = ((y1 > GN - 1) ? GN - 1 : y1) * GN;
    zb[0] = ((z0 < 0) ? 0 : z0) * (GN*GN);  zb[1] = ((z1 > GN - 1) ? GN - 1 : z1) * (GN*GN);

    float occ = 0.0f;
    #pragma unroll
    for (int dzc = 0; dzc < 2; ++dzc)
    #pragma unroll
    for (int dyc = 0; dyc < 2; ++dyc)
    #pragma unroll
    for (int dxc = 0; dxc < 2; ++dxc) {
        float w = (wxv[dxc] * wyv[dyc]) * wzv[dzc];
        occ += w * grid[zb[dzc] + yb[dyc] + xc[dxc]];
    }
    bool maskA = occ > 0.01f;

    __syncthreads();   // w1p/ws2 staged + global_load_lds chunks drained

    // ------- Phase B+C: feat GEMM in two tm-passes (acc[2][4] = 32 AGPR) -----
    const unsigned short* __restrict__ bhiP = (const unsigned short*)(ws + WS_BHI);
    float sgv[4] = {0.0f, 0.0f, 0.0f, 0.0f};   // all reads/writes literal-indexed

    #pragma unroll 1
    for (int ph = 0; ph < 2; ++ph) {
        // coords of the A-fragment rows for THIS pass (literal-indexed pair;
        // ph only appears in the shuffle source lane -> no scratch)
        float cxs[2], cys[2], czs[2];
        #pragma unroll
        for (int tm = 0; tm < 2; ++tm) {
            int src = (ph * 2 + tm) * 16 + c;
            cxs[tm] = __shfl(cx, src, 64);
            cys[tm] = __shfl(cy, src, 64);
            czs[tm] = __shfl(cz, src, 64);
        }

        floatx4 acc[2][4];
        {
            float b2v[4];
            #pragma unroll
            for (int tn = 0; tn < 4; ++tn) b2v[tn] = f_b2[tn * 16 + c];
            #pragma unroll
            for (int tm = 0; tm < 2; ++tm)
                #pragma unroll
                for (int tn = 0; tn < 4; ++tn) {
                    floatx4 v; v[0] = b2v[tn]; v[1] = b2v[tn]; v[2] = b2v[tn]; v[3] = b2v[tn];
                    acc[tm][tn] = v;
                }
        }
        float2v sig2[2];
        sig2[0][0] = 0.0f; sig2[0][1] = 0.0f;
        sig2[1][0] = 0.0f; sig2[1][1] = 0.0f;

        #pragma unroll 2
        for (int kc = 0; kc < 4; ++kc) {
            const int k0  = kc * 32 + q * 8;
            const int pp0 = kc * 16 + q * 4;
            const float4* w1q4 = (const float4*)(fhB + 4096 + pp0 * 32);
            float ws2r[8];
            *(float4*)(ws2r)     = *(const float4*)(fhB + 6144 + k0 * 4);
            *(float4*)(ws2r + 4) = *(const float4*)(fhB + 6144 + k0 * 4 + 16);

            uint32_t packed[2][4];
            #pragma unroll
            for (int p = 0; p < 4; ++p) {
                float4 q0 = w1q4[2 * p];         // {wx0,wx1, wy0,wy1}
                float4 q1 = w1q4[2 * p + 1];     // {wz0,wz1, b0, b1}
                float2v wx2 = {q0.x, q0.y};
                float2v wy2 = {q0.z, q0.w};
                float2v wz2 = {q1.x, q1.y};
                float2v bb2 = {q1.z, q1.w};
                float2v wsp = {ws2r[2 * p], ws2r[2 * p + 1]};
                #pragma unroll
                for (int tm = 0; tm < 2; ++tm) {
                    float2v h2 = bb2;
                    h2 = __builtin_elementwise_fma((float2v){cxs[tm], cxs[tm]}, wx2, h2);
                    h2 = __builtin_elementwise_fma((float2v){cys[tm], cys[tm]}, wy2, h2);
                    h2 = __builtin_elementwise_fma((float2v){czs[tm], czs[tm]}, wz2, h2);
                    h2 = __builtin_elementwise_max(h2, (float2v){0.0f, 0.0f});
                    sig2[tm] = __builtin_elementwise_fma(h2, wsp, sig2[tm]);
                    packed[tm][p] = cvt_pk_bf16(h2[0], h2[1]);
                }
            }
            short8 Ah[2];
            #pragma unroll
            for (int tm = 0; tm < 2; ++tm) {
                uint4 v4 = {packed[tm][0], packed[tm][1], packed[tm][2], packed[tm][3]};
                Ah[tm] = __builtin_bit_cast(short8, v4);
            }
            const int bbase = (kc * 4) * 512 + lane * 8;
            #pragma unroll
            for (int tn = 0; tn < 4; ++tn) {
                // kc<3: LDS-staged copy (wave-uniform scalar branch);
                // kc==3: original global (L2-hot) path.
                short8 bh;
                if (kc < 3)
                    bh = *(const short8*)(fhB + 12288 + kc * 8192 + tn * 1024 + lane * 16);
                else
                    bh = *(const short8*)(bhiP + bbase + tn * 512);
                #pragma unroll
                for (int tm = 0; tm < 2; ++tm)
                    acc[tm][tn] = __builtin_amdgcn_mfma_f32_16x16x32_bf16(Ah[tm], bh, acc[tm][tn], 0, 0, 0);
            }
        }

        // ph==1 epilogue overwrites the staging regions (w1p/ws2 + bhi
        // chunks all live in ph1 rows): all waves' kc-loop reads must
        // complete first.
        if (ph == 1) __syncthreads();

        // phase C for this pass: feat rows -> fh, sigma partials collapse
        #pragma unroll
        for (int tm = 0; tm < 2; ++tm)
            #pragma unroll
            for (int tn = 0; tn < 4; ++tn)
                #pragma unroll
                for (int pr = 0; pr < 2; ++pr) {
                    uint32_t u = cvt_pk_bf16(acc[tm][tn][2 * pr], acc[tm][tn][2 * pr + 1]);
                    int m0 = mbase + (ph * 2 + tm) * 16 + q * 4 + 2 * pr;
                    int i0 = m0 * 64 + c + (((tn * 2) ^ (m0 & 7)) << 3);
                    fh[i0]       = (unsigned short)u;
                    fh[i0 + d01] = (unsigned short)(u >> 16);
                }
        {
            float s0 = sig2[0][0] + sig2[0][1];
            s0 += __shfl_xor(s0, 16);
            s0 += __shfl_xor(s0, 32);
            float s1 = sig2[1][0] + sig2[1][1];
            s1 += __shfl_xor(s1, 16);
            s1 += __shfl_xor(s1, 32);
            if (ph == 0) { sgv[0] = s0; sgv[1] = s1; }   // wave-uniform branch,
            else         { sgv[2] = s0; sgv[3] = s1; }   // literal indices
        }
    }

    // ------- per-lane sigma: sgv[] is q-broadcast; own row = lane -> sgv[q] --
    float av;
    {
        float b2s = *(const float*)(ws + WS_B2S);
        float s01  = (q & 1) ? sgv[1] : sgv[0];
        float s23  = (q & 1) ? sgv[3] : sgv[2];
        float sa = ((q & 2) ? s23 : s01) + b2s;
        float sg = maskA ? (fmaxf(sa, 0.0f) + __logf(1.0f + __expf(-fabsf(sa)))) : 0.0f;
        av = -sg * dist;
    }

    // hd[] uniform loads: latency hides under the scan below
    float hd[4];
    #pragma unroll
    for (int tn = 0; tn < 4; ++tn) {
        int n = tn * 16 + c;
        hd[tn] = r_b1[n] + dxv * r_w1[64 * 64 + n] + dyv * r_w1[65 * 64 + n] + dzv * r_w1[66 * 64 + n];
    }

    // ---------------- transmittance scan, part 1 (intra-wave) ----------------
    float v = av;
    #pragma unroll
    for (int off = 1; off < 64; off <<= 1) {
        float u2 = __shfl_up(v, off);
        if (lane >= off) v += u2;
    }
    // slot-write NOW; barrier + dependent read happen AFTER phase D, so the
    // global L2 round-trip hides under the rgb-hidden GEMM (phase D has no
    // dependence on the scan result -- weight only feeds phase E).
    if (lane == 63 && wv < 3) out[ray * 3 + wv] = v;

    // ---------------- Phase D: rgb-hidden GEMM, two tm-passes ----------------
    const unsigned short* __restrict__ rwP = (const unsigned short*)(ws + WS_RW1);

    #pragma unroll 1
    for (int ph = 0; ph < 2; ++ph) {
        // pass-0 epilogue writes rows mbase+0..31; pass-1 afr reads rows
        // mbase+32..63 -- disjoint, wave-private: no barrier needed.
        short8 afr[2][2];
        #pragma unroll
        for (int tm = 0; tm < 2; ++tm)
            #pragma unroll
            for (int ks = 0; ks < 2; ++ks) {
                int m = mbase + (ph * 2 + tm) * 16 + c;
                int gl = ks * 4 + q;
                afr[tm][ks] = *(const short8*)&fh[m * 64 + ((gl ^ (m & 7)) << 3)];
            }

        floatx4 acc[2][4];
        #pragma unroll
        for (int tm = 0; tm < 2; ++tm)
            #pragma unroll
            for (int tn = 0; tn < 4; ++tn) {
                floatx4 z; z[0] = 0.0f; z[1] = 0.0f; z[2] = 0.0f; z[3] = 0.0f;
                acc[tm][tn] = z;
            }
        #pragma unroll
        for (int ks = 0; ks < 2; ++ks)
            #pragma unroll
            for (int tn = 0; tn < 4; ++tn) {
                short8 rb = *(const short8*)(rwP + ((ks * 4 + tn) * 64 + lane) * 8);
                #pragma unroll
                for (int tm = 0; tm < 2; ++tm)
                    acc[tm][tn] = __builtin_amdgcn_mfma_f32_16x16x32_bf16(afr[tm][ks], rb, acc[tm][tn], 0, 0, 0);
            }

        __builtin_amdgcn_wave_barrier();
        #pragma unroll
        for (int tm = 0; tm < 2; ++tm)
            #pragma unroll
            for (int tn = 0; tn < 4; ++tn)
                #pragma unroll
                for (int pr = 0; pr < 2; ++pr) {
                    float2v a2 = {acc[tm][tn][2 * pr], acc[tm][tn][2 * pr + 1]};
                    a2 = a2 + (float2v){hd[tn], hd[tn]};
                    a2 = __builtin_elementwise_max(a2, (float2v){0.0f, 0.0f});
                    uint32_t u = cvt_pk_bf16(a2[0], a2[1]);
                    int m0 = mbase + (ph * 2 + tm) * 16 + q * 4 + 2 * pr;
                    int i0 = m0 * 64 + c + (((tn * 2) ^ (m0 & 7)) << 3);
                    fh[i0]       = (unsigned short)u;
                    fh[i0 + d01] = (unsigned short)(u >> 16);
                }
    }

    // ---------------- scan part 2: cross-wave prefix (slot read) -------------
    __syncthreads();   // slot writes visible to all waves
    float sw0 = out[ray * 3 + 0];
    float sw1 = out[ray * 3 + 1];
    float sw2 = out[ray * 3 + 2];
    float basev = ((wv > 0) ? sw0 : 0.0f) + ((wv > 1) ? sw1 : 0.0f)
                + ((wv > 2) ? sw2 : 0.0f);
    float excl = __shfl_up(v, 1);
    if (lane == 0) excl = 0.0f;
    float cum    = basev + excl;
    float trans  = __expf(cum);
    float weight = trans * (1.0f - __expf(av));
    bool  mask2  = maskA && (trans > 1e-4f);

    // ---------------- Phase E: final 64->3 via transposed MFMA ---------------
    float wm = mask2 ? weight : 0.0f;
    // weights for rows tn*16+c via wave shuffle (all lanes execute: sources active)
    float wgt[4];
    #pragma unroll
    for (int tn = 0; tn < 4; ++tn) wgt[tn] = __shfl(wm, tn * 16 + c, 64);

    const unsigned short* __restrict__ w2eP = (const unsigned short*)(ws + WS_W2E);
    short8 w2f[2];
    w2f[0] = *(const short8*)(w2eP + (0 * 64 + lane) * 8);
    w2f[1] = *(const short8*)(w2eP + (1 * 64 + lane) * 8);

    floatx4 eacc[4];
    #pragma unroll
    for (int tn = 0; tn < 4; ++tn) {
        floatx4 z; z[0] = 0.0f; z[1] = 0.0f; z[2] = 0.0f; z[3] = 0.0f;
        eacc[tn] = z;
    }
    #pragma unroll
    for (int kf = 0; kf < 2; ++kf)
        #pragma unroll
        for (int tn = 0; tn < 4; ++tn) {
            int m = mbase + tn * 16 + c;
            int gl = kf * 4 + q;
            short8 hb = *(const short8*)&fh[m * 64 + ((gl ^ (m & 7)) << 3)];
            eacc[tn] = __builtin_amdgcn_mfma_f32_16x16x32_bf16(w2f[kf], hb, eacc[tn], 0, 0, 0);
        }

    float r = 0.0f, g = 0.0f, b = 0.0f;
    if (q == 0) {
        float rb0 = r_b2[0], rb1 = r_b2[1], rb2v = r_b2[2];
        #pragma unroll
        for (int tn = 0; tn < 4; ++tn) {
            float wgtv = wgt[tn];
            r += wgtv / (1.0f + __expf(-(eacc[tn][0] + rb0)));
            g += wgtv / (1.0f + __expf(-(eacc[tn][1] + rb1)));
            b += wgtv / (1.0f + __expf(-(eacc[tn][2] + rb2v)));
        }
    }
    #pragma unroll
    for (int off = 8; off > 0; off >>= 1) {
        r += __shfl_xor(r, off);
        g += __shfl_xor(g, off);
        b += __shfl_xor(b, off);
    }
    // cross-wave partials through each wave's own (now dead) fh region
    if (lane == 0) {
        float* pp = (float*)fhB + wv * 2048;   // byte offset wv*8192
        pp[0] = r; pp[1] = g; pp[2] = b;
    }
    __syncthreads();
    if (tid == 0) {
        float* pf = (float*)fhB;
        out[ray * 3 + 0] = pf[0] + pf[2048] + pf[4096] + pf[6144];
        out[ray * 3 + 1] = pf[1] + pf[2049] + pf[4097] + pf[6145];
        out[ray * 3 + 2] = pf[2] + pf[2050] + pf[4098] + pf[6146];
    }
}

extern "C" void kernel_launch(void* const* d_in, const int* in_sizes, int n_in,
                              void* d_out, int out_size, void* d_ws, size_t ws_size,
                              hipStream_t stream) {
    const int n_rays = in_sizes[0] / 3;   // 4096
    nerf_prep<<<1, 256, 0, stream>>>(
        (const float*)d_in[3], (const float*)d_in[4], (const float*)d_in[5],
        (const float*)d_in[6], (const float*)d_in[7], (const float*)d_in[8],
        (const float*)d_in[9], (const float*)d_in[11], (unsigned char*)d_ws);
    nerf_mfma<<<n_rays, 256, 0, stream>>>(
        (const float*)d_in[0],  (const float*)d_in[1],  (const float*)d_in[2],
        (const float*)d_in[6],  (const float*)d_in[9],  (const float*)d_in[10],
        (const float*)d_in[12],
        (const unsigned char*)d_ws, (float*)d_out);
}

// Round 8
// 167.881 us; speedup vs baseline: 2.1608x; 1.0001x over previous
//
#include <hip/hip_runtime.h>
#include <hip/hip_bf16.h>
#include <math.h>
#include <stdint.h>

#define S    256
#define GN   128

typedef __attribute__((ext_vector_type(8))) short  short8;   // 8 bf16
typedef __attribute__((ext_vector_type(4))) float  floatx4;  // MFMA C/D
typedef __attribute__((ext_vector_type(2))) float  float2v;  // v_pk_*_f32 pair

// workspace layout (bytes)
#define WS_BHI 0          // ushort[4*4*64*8] = 16384 B  (f_w2 bf16, frag order)
#define WS_RW1 16384      // ushort[2*4*64*8] =  8192 B  (r_w1 bf16, frag order)
#define WS_B2S 24576      // float  (b2.s_w + s_b)
#define WS_WS2 24592      // float[128]  (W2 @ s_w, fp32)
#define WS_W1P 25104      // float[64*8] pair-interleaved layer-1 = 2048 B
#define WS_W2E 27152      // ushort[2*64*8] = 2048 B (r_w2^T bf16, A-frag order)

__device__ __forceinline__ unsigned short bf16_rtne(float f) {
    uint32_t u = __builtin_bit_cast(uint32_t, f);
    uint32_t r = (u + 0x7fffu + ((u >> 16) & 1u)) >> 16;
    return (unsigned short)r;
}
__device__ __forceinline__ uint32_t cvt_pk_bf16(float a, float b) {
    float2 hh; hh.x = a; hh.y = b;
    __hip_bfloat162 pk = __float22bfloat162_rn(hh);   // v_cvt_pk_bf16_f32
    uint32_t u; __builtin_memcpy(&u, &pk, 4);
    return u;
}

// ---------- pre-pack kernel: weights -> bf16 in MFMA fragment order ----------
__global__ __launch_bounds__(256)
void nerf_prep(const float* __restrict__ f_w1, const float* __restrict__ f_b1,
               const float* __restrict__ f_w2, const float* __restrict__ f_b2,
               const float* __restrict__ s_w,  const float* __restrict__ s_b,
               const float* __restrict__ r_w1, const float* __restrict__ r_w2,
               unsigned char* __restrict__ ws)
{
    const int tid = threadIdx.x;
    if (tid < 128) {                       // ws2 = W2 @ s_w  (fp32) -> global
        float acc = 0.0f;
        for (int n = 0; n < 64; ++n) acc += f_w2[tid * 64 + n] * s_w[n];
        ((float*)(ws + WS_WS2))[tid] = acc;
    } else if (tid == 128) {               // b2s = b2 . s_w + s_b
        float acc = s_b[0];
        for (int n = 0; n < 64; ++n) acc += f_b2[n] * s_w[n];
        *(float*)(ws + WS_B2S) = acc;
    }
    // layer-1 pair-interleaved pack: pair pp covers k=2pp,2pp+1:
    //   {wx0,wx1, wy0,wy1, wz0,wz1, b0,b1}  (aligned float2 pairs for v_pk_fma)
    {
        float* w1pk = (float*)(ws + WS_W1P);
        for (int pp = tid; pp < 64; pp += 256) {
            int k0 = 2 * pp, k1 = 2 * pp + 1;
            w1pk[pp * 8 + 0] = f_w1[k0];       w1pk[pp * 8 + 1] = f_w1[k1];
            w1pk[pp * 8 + 2] = f_w1[128 + k0]; w1pk[pp * 8 + 3] = f_w1[128 + k1];
            w1pk[pp * 8 + 4] = f_w1[256 + k0]; w1pk[pp * 8 + 5] = f_w1[256 + k1];
            w1pk[pp * 8 + 6] = f_b1[k0];       w1pk[pp * 8 + 7] = f_b1[k1];
        }
    }

    unsigned short* bhi = (unsigned short*)(ws + WS_BHI);
    for (int i = tid; i < 8192; i += 256) {
        int j = i & 7, L = (i >> 3) & 63, g = i >> 9;   // g = kc*4 + tn
        int tn = g & 3, kc = g >> 2;
        int q = L >> 4, cc = L & 15;
        int k = kc * 32 + q * 8 + j;
        bhi[i] = bf16_rtne(f_w2[k * 64 + tn * 16 + cc]);
    }
    unsigned short* rw = (unsigned short*)(ws + WS_RW1);
    for (int i = tid; i < 4096; i += 256) {
        int j = i & 7, L = (i >> 3) & 63, g = i >> 9;   // g = ks*4 + tn
        int tn = g & 3, ks = g >> 2;
        int q = L >> 4, cc = L & 15;
        int k = ks * 32 + q * 8 + j;
        rw[i] = bf16_rtne(r_w1[k * 64 + tn * 16 + cc]);
    }
    // r_w2^T in A-fragment order for the phase-E MFMA:
    // A[row=out-channel][k=hidden]; rows 3..15 zero.
    unsigned short* w2e = (unsigned short*)(ws + WS_W2E);
    for (int i = tid; i < 1024; i += 256) {
        int j = i & 7, L = (i >> 3) & 63, kf = i >> 9;
        int q = L >> 4, ch = L & 15;
        int k = kf * 32 + q * 8 + j;
        w2e[i] = (ch < 3) ? bf16_rtne(r_w2[k * 3 + ch]) : (unsigned short)0;
    }
}

// ---------------------------- main kernel -----------------------------------
// R25 = R23 base (87.6 us, best verified) with:
//  (1) R24's bhi LDS staging REVERTED (direct experiment: it cost 2.3 us --
//      the B-frag global loads were already L2-resident and latency-covered
//      by the unroll-2 window; the kc<3 branch broke load hoisting),
//  (2) w1p/ws2 moved to a DEDICATED 2560 B LDS array (total 35328 B; R21
//      proved 4 vs 5 blocks/CU is perf-neutral, so the growth is free).
//      With no fh alias, fh is purely wave-private until the final sPart
//      reduction -> the mid-phase-B `if(ph==1) __syncthreads()` is DELETED.
//      That barrier forced all 4 waves to rendezvous between kc-loop and
//      epilogue every ph1 pass, destroying inter-wave slip; without it,
//      phases B/C/D run barrier-free per wave (only 2 full barriers remain:
//      post-staging and the scan slot-read).
// Tripwire: WRITE_SIZE ~1.3 MB / FETCH ~15 MB (spill detector).
__global__ __launch_bounds__(256, 4)
void nerf_mfma(const float* __restrict__ rays_o,
               const float* __restrict__ rays_d,
               const float* __restrict__ grid,
               const float* __restrict__ f_b2,
               const float* __restrict__ r_w1,
               const float* __restrict__ r_b1,
               const float* __restrict__ r_b2,
               const unsigned char* __restrict__ ws,
               float* __restrict__ out)
{
    // fh: bf16 [256 rows][64], XOR-swizzled in 8-ushort groups: conflict-free
    // b128. Wave-private throughout (no staging alias) until final sPart.
    __shared__ __align__(16) unsigned short fh[256 * 64];
    __shared__ __align__(16) float w1s[640];   // [0..511] w1 pack, [512..639] ws2
    unsigned char* fhB = (unsigned char*)fh;

    const int tid   = threadIdx.x;
    const int ray   = blockIdx.x;
    const int lane  = tid & 63;
    const int wv    = tid >> 6;
    const int q     = lane >> 4;
    const int c     = lane & 15;
    const int mbase = wv * 64;
    const int d01   = 72 - ((c >> 3) << 4);   // i1 - i0 in the epilogue swizzle

    // stage layer-1 pack (2 KB) + ws2 (512 B) into dedicated LDS
    if (tid < 128) {
        ((float4*)w1s)[tid] = ((const float4*)(ws + WS_W1P))[tid];
        w1s[512 + tid]      = ((const float*)(ws + WS_WS2))[tid];
    }

    // ---------------- Phase A: geometry + grid sample (thread = sample) ------
    const float stop = 1.0f - 1.0f / (float)(S + 2);
    const float step = stop / (float)S;
    float u0 = (float)tid * step;
    float u1 = (float)(tid + 1) * step;
    float t    = (u0 < 0.5f) ? 2.0f * u0 : 1.0f / (2.0f - 2.0f * u0);
    float tn_  = (u1 < 0.5f) ? 2.0f * u1 : 1.0f / (2.0f - 2.0f * u1);
    float dist = tn_ - t;

    float ox = rays_o[ray * 3 + 0], oy = rays_o[ray * 3 + 1], oz = rays_o[ray * 3 + 2];
    float dxv = rays_d[ray * 3 + 0], dyv = rays_d[ray * 3 + 1], dzv = rays_d[ray * 3 + 2];

    float px = ox + dxv * t, py = oy + dyv * t, pz = oz + dzv * t;
    float nrm = sqrtf(px * px + py * py + pz * pz);
    float scale = (nrm <= 1.0f) ? 0.5f : (2.0f - 1.0f / nrm) / nrm * 0.5f;
    float cx = px * scale, cy = py * scale, cz = pz * scale;

    float ix = ((cx + 1.0f) * (float)GN - 1.0f) * 0.5f;
    float iy = ((cy + 1.0f) * (float)GN - 1.0f) * 0.5f;
    float iz = ((cz + 1.0f) * (float)GN - 1.0f) * 0.5f;
    float fx0 = floorf(ix), fy0 = floorf(iy), fz0 = floorf(iz);
    float fx = ix - fx0, fy = iy - fy0, fz = iz - fz0;
    int x0 = (int)fx0, y0 = (int)fy0, z0 = (int)fz0;
    int x1 = x0 + 1, y1 = y0 + 1, z1 = z0 + 1;

    // contracted coords strictly inside [-1,1] -> x0 in [-1,127], x1 in [0,128].
    // Only boundary taps can be invalid: zero the per-axis weight, clamp the
    // index. 0*g == 0 exactly; product order (wx*wy)*wz matches branchy version.
    float wxv[2], wyv[2], wzv[2];
    wxv[0] = (x0 >= 0) ? (1.0f - fx) : 0.0f;  wxv[1] = (x1 < GN) ? fx : 0.0f;
    wyv[0] = (y0 >= 0) ? (1.0f - fy) : 0.0f;  wyv[1] = (y1 < GN) ? fy : 0.0f;
    wzv[0] = (z0 >= 0) ? (1.0f - fz) : 0.0f;  wzv[1] = (z1 < GN) ? fz : 0.0f;
    int xc[2], yb[2], zb[2];
    xc[0] = (x0 < 0) ? 0 : x0;              xc[1] = (x1 > GN - 1) ? GN - 1 : x1;
    yb[0] = ((y0 < 0) ? 0 : y0) * GN;       yb[1] = ((y1 > GN - 1) ? GN - 1 : y1) * GN;
    zb[0] = ((z0 < 0) ? 0 : z0) * (GN*GN);  zb[1] = ((z1 > GN - 1) ? GN - 1 : z1) * (GN*GN);

    float occ = 0.0f;
    #pragma unroll
    for (int dzc = 0; dzc < 2; ++dzc)
    #pragma unroll
    for (int dyc = 0; dyc < 2; ++dyc)
    #pragma unroll
    for (int dxc = 0; dxc < 2; ++dxc) {
        float w = (wxv[dxc] * wyv[dyc]) * wzv[dzc];
        occ += w * grid[zb[dzc] + yb[dyc] + xc[dxc]];
    }
    bool maskA = occ > 0.01f;

    __syncthreads();   // w1s staged

    // ------- Phase B+C: feat GEMM in two tm-passes (acc[2][4] = 32 AGPR) -----
    const unsigned short* __restrict__ bhiP = (const unsigned short*)(ws + WS_BHI);
    float sgv[4] = {0.0f, 0.0f, 0.0f, 0.0f};   // all reads/writes literal-indexed

    #pragma unroll 1
    for (int ph = 0; ph < 2; ++ph) {
        // coords of the A-fragment rows for THIS pass (literal-indexed pair;
        // ph only appears in the shuffle source lane -> no scratch)
        float cxs[2], cys[2], czs[2];
        #pragma unroll
        for (int tm = 0; tm < 2; ++tm) {
            int src = (ph * 2 + tm) * 16 + c;
            cxs[tm] = __shfl(cx, src, 64);
            cys[tm] = __shfl(cy, src, 64);
            czs[tm] = __shfl(cz, src, 64);
        }

        floatx4 acc[2][4];
        {
            float b2v[4];
            #pragma unroll
            for (int tn = 0; tn < 4; ++tn) b2v[tn] = f_b2[tn * 16 + c];
            #pragma unroll
            for (int tm = 0; tm < 2; ++tm)
                #pragma unroll
                for (int tn = 0; tn < 4; ++tn) {
                    floatx4 v; v[0] = b2v[tn]; v[1] = b2v[tn]; v[2] = b2v[tn]; v[3] = b2v[tn];
                    acc[tm][tn] = v;
                }
        }
        float2v sig2[2];
        sig2[0][0] = 0.0f; sig2[0][1] = 0.0f;
        sig2[1][0] = 0.0f; sig2[1][1] = 0.0f;

        #pragma unroll 2
        for (int kc = 0; kc < 4; ++kc) {
            const int k0  = kc * 32 + q * 8;
            const int pp0 = kc * 16 + q * 4;
            const float4* w1q4 = (const float4*)&w1s[pp0 * 8];
            float ws2r[8];
            *(float4*)(ws2r)     = *(const float4*)&w1s[512 + k0];
            *(float4*)(ws2r + 4) = *(const float4*)&w1s[512 + k0 + 4];

            uint32_t packed[2][4];
            #pragma unroll
            for (int p = 0; p < 4; ++p) {
                float4 q0 = w1q4[2 * p];         // {wx0,wx1, wy0,wy1}
                float4 q1 = w1q4[2 * p + 1];     // {wz0,wz1, b0, b1}
                float2v wx2 = {q0.x, q0.y};
                float2v wy2 = {q0.z, q0.w};
                float2v wz2 = {q1.x, q1.y};
                float2v bb2 = {q1.z, q1.w};
                float2v wsp = {ws2r[2 * p], ws2r[2 * p + 1]};
                #pragma unroll
                for (int tm = 0; tm < 2; ++tm) {
                    float2v h2 = bb2;
                    h2 = __builtin_elementwise_fma((float2v){cxs[tm], cxs[tm]}, wx2, h2);
                    h2 = __builtin_elementwise_fma((float2v){cys[tm], cys[tm]}, wy2, h2);
                    h2 = __builtin_elementwise_fma((float2v){czs[tm], czs[tm]}, wz2, h2);
                    h2 = __builtin_elementwise_max(h2, (float2v){0.0f, 0.0f});
                    sig2[tm] = __builtin_elementwise_fma(h2, wsp, sig2[tm]);
                    packed[tm][p] = cvt_pk_bf16(h2[0], h2[1]);
                }
            }
            short8 Ah[2];
            #pragma unroll
            for (int tm = 0; tm < 2; ++tm) {
                uint4 v4 = {packed[tm][0], packed[tm][1], packed[tm][2], packed[tm][3]};
                Ah[tm] = __builtin_bit_cast(short8, v4);
            }
            const int bbase = (kc * 4) * 512 + lane * 8;
            #pragma unroll
            for (int tn = 0; tn < 4; ++tn) {
                short8 bh = *(const short8*)(bhiP + bbase + tn * 512);
                #pragma unroll
                for (int tm = 0; tm < 2; ++tm)
                    acc[tm][tn] = __builtin_amdgcn_mfma_f32_16x16x32_bf16(Ah[tm], bh, acc[tm][tn], 0, 0, 0);
            }
        }

        // NO barrier here: fh is wave-private (staging lives in w1s now).

        // phase C for this pass: feat rows -> fh, sigma partials collapse
        #pragma unroll
        for (int tm = 0; tm < 2; ++tm)
            #pragma unroll
            for (int tn = 0; tn < 4; ++tn)
                #pragma unroll
                for (int pr = 0; pr < 2; ++pr) {
                    uint32_t u = cvt_pk_bf16(acc[tm][tn][2 * pr], acc[tm][tn][2 * pr + 1]);
                    int m0 = mbase + (ph * 2 + tm) * 16 + q * 4 + 2 * pr;
                    int i0 = m0 * 64 + c + (((tn * 2) ^ (m0 & 7)) << 3);
                    fh[i0]       = (unsigned short)u;
                    fh[i0 + d01] = (unsigned short)(u >> 16);
                }
        {
            float s0 = sig2[0][0] + sig2[0][1];
            s0 += __shfl_xor(s0, 16);
            s0 += __shfl_xor(s0, 32);
            float s1 = sig2[1][0] + sig2[1][1];
            s1 += __shfl_xor(s1, 16);
            s1 += __shfl_xor(s1, 32);
            if (ph == 0) { sgv[0] = s0; sgv[1] = s1; }   // wave-uniform branch,
            else         { sgv[2] = s0; sgv[3] = s1; }   // literal indices
        }
    }

    // ------- per-lane sigma: sgv[] is q-broadcast; own row = lane -> sgv[q] --
    float av;
    {
        float b2s = *(const float*)(ws + WS_B2S);
        float s01  = (q & 1) ? sgv[1] : sgv[0];
        float s23  = (q & 1) ? sgv[3] : sgv[2];
        float sa = ((q & 2) ? s23 : s01) + b2s;
        float sg = maskA ? (fmaxf(sa, 0.0f) + __logf(1.0f + __expf(-fabsf(sa)))) : 0.0f;
        av = -sg * dist;
    }

    // hd[] uniform loads: latency hides under the scan below
    float hd[4];
    #pragma unroll
    for (int tn = 0; tn < 4; ++tn) {
        int n = tn * 16 + c;
        hd[tn] = r_b1[n] + dxv * r_w1[64 * 64 + n] + dyv * r_w1[65 * 64 + n] + dzv * r_w1[66 * 64 + n];
    }

    // ---------------- transmittance scan, part 1 (intra-wave) ----------------
    float v = av;
    #pragma unroll
    for (int off = 1; off < 64; off <<= 1) {
        float u2 = __shfl_up(v, off);
        if (lane >= off) v += u2;
    }
    // slot-write NOW; barrier + dependent read happen AFTER phase D, so the
    // global L2 round-trip hides under the rgb-hidden GEMM (phase D has no
    // dependence on the scan result -- weight only feeds phase E).
    if (lane == 63 && wv < 3) out[ray * 3 + wv] = v;

    // ---------------- Phase D: rgb-hidden GEMM, two tm-passes ----------------
    const unsigned short* __restrict__ rwP = (const unsigned short*)(ws + WS_RW1);

    #pragma unroll 1
    for (int ph = 0; ph < 2; ++ph) {
        // pass-0 epilogue writes rows mbase+0..31; pass-1 afr reads rows
        // mbase+32..63 -- disjoint, wave-private: no barrier needed.
        short8 afr[2][2];
        #pragma unroll
        for (int tm = 0; tm < 2; ++tm)
            #pragma unroll
            for (int ks = 0; ks < 2; ++ks) {
                int m = mbase + (ph * 2 + tm) * 16 + c;
                int gl = ks * 4 + q;
                afr[tm][ks] = *(const short8*)&fh[m * 64 + ((gl ^ (m & 7)) << 3)];
            }

        floatx4 acc[2][4];
        #pragma unroll
        for (int tm = 0; tm < 2; ++tm)
            #pragma unroll
            for (int tn = 0; tn < 4; ++tn) {
                floatx4 z; z[0] = 0.0f; z[1] = 0.0f; z[2] = 0.0f; z[3] = 0.0f;
                acc[tm][tn] = z;
            }
        #pragma unroll
        for (int ks = 0; ks < 2; ++ks)
            #pragma unroll
            for (int tn = 0; tn < 4; ++tn) {
                short8 rb = *(const short8*)(rwP + ((ks * 4 + tn) * 64 + lane) * 8);
                #pragma unroll
                for (int tm = 0; tm < 2; ++tm)
                    acc[tm][tn] = __builtin_amdgcn_mfma_f32_16x16x32_bf16(afr[tm][ks], rb, acc[tm][tn], 0, 0, 0);
            }

        __builtin_amdgcn_wave_barrier();
        #pragma unroll
        for (int tm = 0; tm < 2; ++tm)
            #pragma unroll
            for (int tn = 0; tn < 4; ++tn)
                #pragma unroll
                for (int pr = 0; pr < 2; ++pr) {
                    float2v a2 = {acc[tm][tn][2 * pr], acc[tm][tn][2 * pr + 1]};
                    a2 = a2 + (float2v){hd[tn], hd[tn]};
                    a2 = __builtin_elementwise_max(a2, (float2v){0.0f, 0.0f});
                    uint32_t u = cvt_pk_bf16(a2[0], a2[1]);
                    int m0 = mbase + (ph * 2 + tm) * 16 + q * 4 + 2 * pr;
                    int i0 = m0 * 64 + c + (((tn * 2) ^ (m0 & 7)) << 3);
                    fh[i0]       = (unsigned short)u;
                    fh[i0 + d01] = (unsigned short)(u >> 16);
                }
    }

    // ---------------- scan part 2: cross-wave prefix (slot read) -------------
    __syncthreads();   // slot writes visible to all waves
    float sw0 = out[ray * 3 + 0];
    float sw1 = out[ray * 3 + 1];
    float sw2 = out[ray * 3 + 2];
    float basev = ((wv > 0) ? sw0 : 0.0f) + ((wv > 1) ? sw1 : 0.0f)
                + ((wv > 2) ? sw2 : 0.0f);
    float excl = __shfl_up(v, 1);
    if (lane == 0) excl = 0.0f;
    float cum    = basev + excl;
    float trans  = __expf(cum);
    float weight = trans * (1.0f - __expf(av));
    bool  mask2  = maskA && (trans > 1e-4f);

    // ---------------- Phase E: final 64->3 via transposed MFMA ---------------
    float wm = mask2 ? weight : 0.0f;
    // weights for rows tn*16+c via wave shuffle (all lanes execute: sources active)
    float wgt[4];
    #pragma unroll
    for (int tn = 0; tn < 4; ++tn) wgt[tn] = __shfl(wm, tn * 16 + c, 64);

    const unsigned short* __restrict__ w2eP = (const unsigned short*)(ws + WS_W2E);
    short8 w2f[2];
    w2f[0] = *(const short8*)(w2eP + (0 * 64 + lane) * 8);
    w2f[1] = *(const short8*)(w2eP + (1 * 64 + lane) * 8);

    floatx4 eacc[4];
    #pragma unroll
    for (int tn = 0; tn < 4; ++tn) {
        floatx4 z; z[0] = 0.0f; z[1] = 0.0f; z[2] = 0.0f; z[3] = 0.0f;
        eacc[tn] = z;
    }
    #pragma unroll
    for (int kf = 0; kf < 2; ++kf)
        #pragma unroll
        for (int tn = 0; tn < 4; ++tn) {
            int m = mbase + tn * 16 + c;
            int gl = kf * 4 + q;
            short8 hb = *(const short8*)&fh[m * 64 + ((gl ^ (m & 7)) << 3)];
            eacc[tn] = __builtin_amdgcn_mfma_f32_16x16x32_bf16(w2f[kf], hb, eacc[tn], 0, 0, 0);
        }

    float r = 0.0f, g = 0.0f, b = 0.0f;
    if (q == 0) {
        float rb0 = r_b2[0], rb1 = r_b2[1], rb2v = r_b2[2];
        #pragma unroll
        for (int tn = 0; tn < 4; ++tn) {
            float wgtv = wgt[tn];
            r += wgtv / (1.0f + __expf(-(eacc[tn][0] + rb0)));
            g += wgtv / (1.0f + __expf(-(eacc[tn][1] + rb1)));
            b += wgtv / (1.0f + __expf(-(eacc[tn][2] + rb2v)));
        }
    }
    #pragma unroll
    for (int off = 8; off > 0; off >>= 1) {
        r += __shfl_xor(r, off);
        g += __shfl_xor(g, off);
        b += __shfl_xor(b, off);
    }
    // cross-wave partials through each wave's own (now dead) fh region
    if (lane == 0) {
        float* pp = (float*)fhB + wv * 2048;   // byte offset wv*8192
        pp[0] = r; pp[1] = g; pp[2] = b;
    }
    __syncthreads();
    if (tid == 0) {
        float* pf = (float*)fhB;
        out[ray * 3 + 0] = pf[0] + pf[2048] + pf[4096] + pf[6144];
        out[ray * 3 + 1] = pf[1] + pf[2049] + pf[4097] + pf[6145];
        out[ray * 3 + 2] = pf[2] + pf[2050] + pf[4098] + pf[6146];
    }
}

extern "C" void kernel_launch(void* const* d_in, const int* in_sizes, int n_in,
                              void* d_out, int out_size, void* d_ws, size_t ws_size,
                              hipStream_t stream) {
    const int n_rays = in_sizes[0] / 3;   // 4096
    nerf_prep<<<1, 256, 0, stream>>>(
        (const float*)d_in[3], (const float*)d_in[4], (const float*)d_in[5],
        (const float*)d_in[6], (const float*)d_in[7], (const float*)d_in[8],
        (const float*)d_in[9], (const float*)d_in[11], (unsigned char*)d_ws);
    nerf_mfma<<<n_rays, 256, 0, stream>>>(
        (const float*)d_in[0],  (const float*)d_in[1],  (const float*)d_in[2],
        (const float*)d_in[6],  (const float*)d_in[9],  (const float*)d_in[10],
        (const float*)d_in[12],
        (const unsigned char*)d_ws, (float*)d_out);
}